// Round 1
// 935.281 us; speedup vs baseline: 1.2678x; 1.2678x over previous
//
#include <hip/hip_runtime.h>
#include <hip/hip_fp16.h>

// GraphEncoder: node linear; 3x GINEConv(eps=0, nn=Linear+LeakyReLU); skip; head Linear+LayerNorm.
// R9: k_gather latency/issue attack. Counters showed 202us/dispatch at 18% HBM, 48% VALU, 0 MFMA
//     -> latency-bound with VALU floor. Two changes:
//     (1) readfirstlane-seeded wave-uniformity: p/csr_src/csr_a16 loads become s_load_* (scalar
//         path), killing per-lane 64b address math + broadcast vector loads. fdot2 reads the
//         edge-attr operand from SGPRs (VOP3P: 1 SGPR src allowed).
//     (2) 4-edge unroll: 4 independent random h16 256B gathers in flight per wave (was 2).
// edge_index arrives as int32 (harness converts int64 inputs).
constexpr int N      = 100000;
constexpr int E      = 1600000;
constexpr int F_IN   = 64;
constexpr int F_EDGE = 16;
constexpr int H      = 128;
constexpr int NB     = (N + 255) / 256;     // 391 scan blocks
constexpr float NEG  = 0.01f;
constexpr float EPS  = 1e-5f;

typedef _Float16 hv2 __attribute__((ext_vector_type(2)));

// ================= CSR build =================
__global__ __launch_bounds__(256) void k_zero(int* __restrict__ p, int n) {
  int i = blockIdx.x * 256 + threadIdx.x;
  if (i < n) p[i] = 0;
}

__global__ __launch_bounds__(256) void k_hist(const int* __restrict__ eidx, int* __restrict__ deg) {
  int i = blockIdx.x * 256 + threadIdx.x;
  if (i < E) atomicAdd(&deg[eidx[E + i]], 1);
}

__global__ __launch_bounds__(256) void k_scan_block(const int* __restrict__ deg,
    int* __restrict__ excl, int* __restrict__ bsum) {
  __shared__ int s[256];
  int t = threadIdx.x, i = blockIdx.x * 256 + t;
  int v = (i < N) ? deg[i] : 0;
  s[t] = v; __syncthreads();
#pragma unroll
  for (int off = 1; off < 256; off <<= 1) {
    int u = (t >= off) ? s[t - off] : 0;
    __syncthreads();
    s[t] += u;
    __syncthreads();
  }
  if (i < N) excl[i] = s[t] - v;
  if (t == 255) bsum[blockIdx.x] = s[255];
}

__global__ __launch_bounds__(512) void k_scan_top(const int* __restrict__ bsum, int* __restrict__ boff) {
  __shared__ int s[512];
  int t = threadIdx.x;
  int v = (t < NB) ? bsum[t] : 0;
  s[t] = v; __syncthreads();
#pragma unroll
  for (int off = 1; off < 512; off <<= 1) {
    int u = (t >= off) ? s[t - off] : 0;
    __syncthreads();
    s[t] += u;
    __syncthreads();
  }
  if (t < NB) boff[t] = s[t] - v;
}

__global__ __launch_bounds__(256) void k_scan_add(const int* __restrict__ excl,
    const int* __restrict__ boff, int* __restrict__ rowptr, int* __restrict__ cursor) {
  int i = blockIdx.x * 256 + threadIdx.x;
  if (i < N) {
    int r = excl[i] + boff[i >> 8];
    rowptr[i] = r;
    cursor[i] = r;
  }
}

// scatter: CSR-slot src index + edge_attr row converted to fp16 (2x uint4 = 32B/edge)
__global__ __launch_bounds__(256) void k_scatter(const int* __restrict__ eidx,
    const float* __restrict__ edge_attr, int* __restrict__ cursor,
    int* __restrict__ csr_src, uint4* __restrict__ csr_a16) {
  int i = blockIdx.x * 256 + threadIdx.x;
  if (i >= E) return;
  int d = eidx[E + i];
  int pos = atomicAdd(&cursor[d], 1);
  csr_src[pos] = eidx[i];
  const float4* ar = (const float4*)(edge_attr + (size_t)i * F_EDGE);
  float4 f0 = ar[0], f1 = ar[1], f2 = ar[2], f3 = ar[3];
  __half2 hh[8];
  hh[0] = __float22half2_rn(make_float2(f0.x, f0.y));
  hh[1] = __float22half2_rn(make_float2(f0.z, f0.w));
  hh[2] = __float22half2_rn(make_float2(f1.x, f1.y));
  hh[3] = __float22half2_rn(make_float2(f1.z, f1.w));
  hh[4] = __float22half2_rn(make_float2(f2.x, f2.y));
  hh[5] = __float22half2_rn(make_float2(f2.z, f2.w));
  hh[6] = __float22half2_rn(make_float2(f3.x, f3.y));
  hh[7] = __float22half2_rn(make_float2(f3.z, f3.w));
  const uint4* u = (const uint4*)hh;
  csr_a16[2 * (size_t)pos + 0] = u[0];
  csr_a16[2 * (size_t)pos + 1] = u[1];
}

// ================= node linear: h = x @ W_node + b  (32 nodes/block, 4n x 4c per thread) =================
__global__ __launch_bounds__(256) void k_node_linear(
    const float* __restrict__ x, const float* __restrict__ W,
    const float* __restrict__ b, float* __restrict__ h, __half* __restrict__ h16) {
  __shared__ float xs[32][F_IN];             // 8 KB
  int i0 = blockIdx.x * 32;
  {
    const float4* s4 = (const float4*)(x + (size_t)i0 * F_IN);
    float4* t4 = (float4*)xs;
#pragma unroll
    for (int r = 0; r < 2; ++r) t4[threadIdx.x + 256 * r] = s4[threadIdx.x + 256 * r];
  }
  __syncthreads();
  int c0 = (threadIdx.x & 31) * 4;
  int n0 = (threadIdx.x >> 5) * 4;
  float4 bb = *(const float4*)(b + c0);
  float4 acc[4] = {bb, bb, bb, bb};
#pragma unroll 4
  for (int k = 0; k < F_IN; ++k) {
    float4 w4 = *(const float4*)(W + k * H + c0);   // coalesced; reused by 4 nodes
#pragma unroll
    for (int j = 0; j < 4; ++j) {
      float s = xs[n0 + j][k];                      // LDS broadcast
      acc[j].x = fmaf(s, w4.x, acc[j].x);
      acc[j].y = fmaf(s, w4.y, acc[j].y);
      acc[j].z = fmaf(s, w4.z, acc[j].z);
      acc[j].w = fmaf(s, w4.w, acc[j].w);
    }
  }
#pragma unroll
  for (int j = 0; j < 4; ++j) {
    size_t idx = (size_t)(i0 + n0 + j) * H + c0;
    *(float4*)(h + idx) = acc[j];
    __half2* ph = (__half2*)(h16 + idx);
    ph[0] = __float22half2_rn(make_float2(acc[j].x, acc[j].y));
    ph[1] = __float22half2_rn(make_float2(acc[j].z, acc[j].w));
  }
}

// ================= gather: sum[i] = h[i] + sum_in relu(h16[src] + a16@We + be) =================
// 1 wave per node; lane owns channels {2*lane, 2*lane+1}; We as fp16 k-pairs -> v_dot2_f32_f16.
// p / csr_src / csr_a16 are wave-uniform: readfirstlane seeds uniformity so they lower to
// s_load_* (scalar cache); h16 gather is the only per-lane vector load. 4-edge unroll keeps
// 4 random 256B gathers in flight per wave.
__device__ __forceinline__ void dot16(uint4 A0, uint4 A1,
                                      const hv2* __restrict__ wA, const hv2* __restrict__ wB,
                                      float& tx, float& ty) {
  unsigned u[8] = {A0.x, A0.y, A0.z, A0.w, A1.x, A1.y, A1.z, A1.w};
#pragma unroll
  for (int j = 0; j < 8; ++j) {
    hv2 a = __builtin_bit_cast(hv2, u[j]);
    tx = __builtin_amdgcn_fdot2(a, wA[j], tx, false);
    ty = __builtin_amdgcn_fdot2(a, wB[j], ty, false);
  }
}

__global__ __launch_bounds__(256) void k_gather(
    const int* __restrict__ rowptr, const int* __restrict__ deg,
    const int* __restrict__ csr_src, const uint4* __restrict__ csr_a16,
    const __half2* __restrict__ h16, const float* __restrict__ We,
    const float* __restrict__ be, const float* __restrict__ h,
    float* __restrict__ sum) {
  int lane = threadIdx.x & 63;
  int node = (blockIdx.x * 256 + threadIdx.x) >> 6;
  if (node >= N) return;
  int c0 = 2 * lane;
  hv2 wA[8], wB[8];                          // We columns c0,c0+1 packed as k-pairs
#pragma unroll
  for (int j = 0; j < 8; ++j) {
    hv2 a, bq;
    a[0]  = (_Float16)We[(2 * j) * H + c0];
    a[1]  = (_Float16)We[(2 * j + 1) * H + c0];
    bq[0] = (_Float16)We[(2 * j) * H + c0 + 1];
    bq[1] = (_Float16)We[(2 * j + 1) * H + c0 + 1];
    wA[j] = a; wB[j] = bq;
  }
  float2 bias = ((const float2*)be)[lane];
  float2 acc = ((const float2*)(h + (size_t)node * H))[lane];   // self term, fp32
  // Whole wave shares one node -> these are wave-uniform; seed the uniformity analysis so all
  // downstream csr_src / csr_a16 loads become scalar (s_load) with SGPR-resident results.
  int p    = __builtin_amdgcn_readfirstlane(rowptr[node]);
  int dg   = __builtin_amdgcn_readfirstlane(deg[node]);
  int pend = p + dg;
  for (; p + 4 <= pend; p += 4) {
    int s0 = csr_src[p + 0];
    int s1 = csr_src[p + 1];
    int s2 = csr_src[p + 2];
    int s3 = csr_src[p + 3];
    __half2 g0 = h16[(size_t)s0 * 64 + lane];   // 4 independent random 256B/wave gathers
    __half2 g1 = h16[(size_t)s1 * 64 + lane];
    __half2 g2 = h16[(size_t)s2 * 64 + lane];
    __half2 g3 = h16[(size_t)s3 * 64 + lane];
    uint4 A0 = csr_a16[2 * (size_t)p + 0];      // wave-uniform sequential stream (scalar path)
    uint4 A1 = csr_a16[2 * (size_t)p + 1];
    uint4 B0 = csr_a16[2 * (size_t)p + 2];
    uint4 B1 = csr_a16[2 * (size_t)p + 3];
    uint4 C0 = csr_a16[2 * (size_t)p + 4];
    uint4 C1 = csr_a16[2 * (size_t)p + 5];
    uint4 D0 = csr_a16[2 * (size_t)p + 6];
    uint4 D1 = csr_a16[2 * (size_t)p + 7];
    float t0x = bias.x, t0y = bias.y;
    float t1x = bias.x, t1y = bias.y;
    float t2x = bias.x, t2y = bias.y;
    float t3x = bias.x, t3y = bias.y;
    dot16(A0, A1, wA, wB, t0x, t0y);
    dot16(B0, B1, wA, wB, t1x, t1y);
    dot16(C0, C1, wA, wB, t2x, t2y);
    dot16(D0, D1, wA, wB, t3x, t3y);
    float2 f0 = __half22float2(g0);
    float2 f1 = __half22float2(g1);
    float2 f2 = __half22float2(g2);
    float2 f3 = __half22float2(g3);
    acc.x += fmaxf(f0.x + t0x, 0.f) + fmaxf(f1.x + t1x, 0.f)
           + fmaxf(f2.x + t2x, 0.f) + fmaxf(f3.x + t3x, 0.f);
    acc.y += fmaxf(f0.y + t0y, 0.f) + fmaxf(f1.y + t1y, 0.f)
           + fmaxf(f2.y + t2y, 0.f) + fmaxf(f3.y + t3y, 0.f);
  }
  for (; p + 2 <= pend; p += 2) {
    int s0 = csr_src[p];
    int s1 = csr_src[p + 1];
    __half2 g0 = h16[(size_t)s0 * 64 + lane];
    __half2 g1 = h16[(size_t)s1 * 64 + lane];
    uint4 A0 = csr_a16[2 * (size_t)p + 0];
    uint4 A1 = csr_a16[2 * (size_t)p + 1];
    uint4 B0 = csr_a16[2 * (size_t)p + 2];
    uint4 B1 = csr_a16[2 * (size_t)p + 3];
    float t0x = bias.x, t0y = bias.y;
    float t1x = bias.x, t1y = bias.y;
    dot16(A0, A1, wA, wB, t0x, t0y);
    dot16(B0, B1, wA, wB, t1x, t1y);
    float2 gf0 = __half22float2(g0);
    float2 gf1 = __half22float2(g1);
    acc.x += fmaxf(gf0.x + t0x, 0.f) + fmaxf(gf1.x + t1x, 0.f);
    acc.y += fmaxf(gf0.y + t0y, 0.f) + fmaxf(gf1.y + t1y, 0.f);
  }
  for (; p < pend; ++p) {
    int s = csr_src[p];
    __half2 g = h16[(size_t)s * 64 + lane];
    uint4 A0 = csr_a16[2 * (size_t)p + 0];
    uint4 A1 = csr_a16[2 * (size_t)p + 1];
    float tx = bias.x, ty = bias.y;
    dot16(A0, A1, wA, wB, tx, ty);
    float2 gf = __half22float2(g);
    acc.x += fmaxf(gf.x + tx, 0.f);
    acc.y += fmaxf(gf.y + ty, 0.f);
  }
  ((float2*)sum)[(size_t)node * 64 + lane] = acc;
}

// ================= node update: h = leaky_relu(sum @ W_conv[l] + b)  (32 nodes/block) =================
__global__ __launch_bounds__(256) void k_node_update(
    const float* __restrict__ sum, const float* __restrict__ W,
    const float* __restrict__ b, float* __restrict__ hout, __half* __restrict__ h16) {
  __shared__ float t[32][H];                 // 16 KB
  int i0 = blockIdx.x * 32;
  {
    const float4* s4 = (const float4*)(sum + (size_t)i0 * H);
    float4* t4 = (float4*)t;
#pragma unroll
    for (int r = 0; r < 4; ++r) t4[threadIdx.x + 256 * r] = s4[threadIdx.x + 256 * r];
  }
  __syncthreads();
  int c0 = (threadIdx.x & 31) * 4;
  int n0 = (threadIdx.x >> 5) * 4;
  float4 bb = *(const float4*)(b + c0);
  float4 acc[4] = {bb, bb, bb, bb};
#pragma unroll 4
  for (int k = 0; k < H; ++k) {
    float4 w4 = *(const float4*)(W + k * H + c0);   // coalesced; reused by 4 nodes
#pragma unroll
    for (int j = 0; j < 4; ++j) {
      float s = t[n0 + j][k];                       // LDS broadcast
      acc[j].x = fmaf(s, w4.x, acc[j].x);
      acc[j].y = fmaf(s, w4.y, acc[j].y);
      acc[j].z = fmaf(s, w4.z, acc[j].z);
      acc[j].w = fmaf(s, w4.w, acc[j].w);
    }
  }
#pragma unroll
  for (int j = 0; j < 4; ++j) {
    float4 a = acc[j];
    a.x = a.x >= 0.f ? a.x : NEG * a.x;
    a.y = a.y >= 0.f ? a.y : NEG * a.y;
    a.z = a.z >= 0.f ? a.z : NEG * a.z;
    a.w = a.w >= 0.f ? a.w : NEG * a.w;
    size_t idx = (size_t)(i0 + n0 + j) * H + c0;
    *(float4*)(hout + idx) = a;
    __half2* ph = (__half2*)(h16 + idx);
    ph[0] = __float22half2_rn(make_float2(a.x, a.y));
    ph[1] = __float22half2_rn(make_float2(a.z, a.w));
  }
}

// ================= head: skip recomputed; y = (skip+h)@W_head + b; LayerNorm  (32 nodes/block) =================
__global__ __launch_bounds__(256) void k_head(
    const float* __restrict__ x, const float* __restrict__ Wn,
    const float* __restrict__ bn, const float* __restrict__ hfin,
    const float* __restrict__ W, const float* __restrict__ b,
    const float* __restrict__ gamma, const float* __restrict__ beta,
    float* __restrict__ out) {
  __shared__ float xs[32][F_IN];             // 8 KB
  __shared__ float t[32][H];                 // 16 KB
  int i0 = blockIdx.x * 32;
  {
    const float4* s4 = (const float4*)(x + (size_t)i0 * F_IN);
    float4* t4 = (float4*)xs;
#pragma unroll
    for (int r = 0; r < 2; ++r) t4[threadIdx.x + 256 * r] = s4[threadIdx.x + 256 * r];
  }
  __syncthreads();
  int c0 = (threadIdx.x & 31) * 4;
  int n0 = (threadIdx.x >> 5) * 4;
  // skip = x @ W_node + b_node, 4 nodes x 4 channels, W reused across nodes
  {
    float4 bb = *(const float4*)(bn + c0);
    float4 acc[4] = {bb, bb, bb, bb};
#pragma unroll 4
    for (int k = 0; k < F_IN; ++k) {
      float4 w4 = *(const float4*)(Wn + k * H + c0);
#pragma unroll
      for (int j = 0; j < 4; ++j) {
        float s = xs[n0 + j][k];                    // LDS broadcast
        acc[j].x = fmaf(s, w4.x, acc[j].x);
        acc[j].y = fmaf(s, w4.y, acc[j].y);
        acc[j].z = fmaf(s, w4.z, acc[j].z);
        acc[j].w = fmaf(s, w4.w, acc[j].w);
      }
    }
#pragma unroll
    for (int j = 0; j < 4; ++j) {
      float4 hf = *(const float4*)(hfin + (size_t)(i0 + n0 + j) * H + c0);
      acc[j].x += hf.x; acc[j].y += hf.y; acc[j].z += hf.z; acc[j].w += hf.w;
      *(float4*)&t[n0 + j][c0] = acc[j];
    }
  }
  __syncthreads();
  float4 bh = *(const float4*)(b + c0);
  float4 acc[4] = {bh, bh, bh, bh};
#pragma unroll 4
  for (int k = 0; k < H; ++k) {
    float4 w4 = *(const float4*)(W + k * H + c0);   // coalesced; reused by 4 nodes
#pragma unroll
    for (int j = 0; j < 4; ++j) {
      float s = t[n0 + j][k];                       // LDS broadcast
      acc[j].x = fmaf(s, w4.x, acc[j].x);
      acc[j].y = fmaf(s, w4.y, acc[j].y);
      acc[j].z = fmaf(s, w4.z, acc[j].z);
      acc[j].w = fmaf(s, w4.w, acc[j].w);
    }
  }
  // LayerNorm: channels of node n0+j live in acc[j] across the 32 lanes of this half-wave
  float4 g4 = *(const float4*)(gamma + c0);
  float4 b4 = *(const float4*)(beta + c0);
#pragma unroll
  for (int j = 0; j < 4; ++j) {
    float S  = acc[j].x + acc[j].y + acc[j].z + acc[j].w;
    float S2 = acc[j].x * acc[j].x + acc[j].y * acc[j].y
             + acc[j].z * acc[j].z + acc[j].w * acc[j].w;
#pragma unroll
    for (int off = 16; off > 0; off >>= 1) {
      S  += __shfl_down(S, off, 32);
      S2 += __shfl_down(S2, off, 32);
    }
    S  = __shfl(S, 0, 32);
    S2 = __shfl(S2, 0, 32);
    float mu  = S * (1.f / H);
    float var = S2 * (1.f / H) - mu * mu;
    float inv = rsqrtf(var + EPS);
    float4 o;
    o.x = (acc[j].x - mu) * inv * g4.x + b4.x;
    o.y = (acc[j].y - mu) * inv * g4.y + b4.y;
    o.z = (acc[j].z - mu) * inv * g4.z + b4.z;
    o.w = (acc[j].w - mu) * inv * g4.w + b4.w;
    *(float4*)(out + (size_t)(i0 + n0 + j) * H + c0) = o;
  }
}

extern "C" void kernel_launch(void* const* d_in, const int* in_sizes, int n_in,
                              void* d_out, int out_size, void* d_ws, size_t ws_size,
                              hipStream_t stream) {
  const float* x         = (const float*)d_in[0];
  const float* edge_attr = (const float*)d_in[1];
  const int*   eidx      = (const int*)d_in[2];      // int32 (harness-converted)
  const float* W_node    = (const float*)d_in[3];
  const float* b_node    = (const float*)d_in[4];
  const float* W_edge    = (const float*)d_in[5];
  const float* b_edge    = (const float*)d_in[6];
  const float* W_conv    = (const float*)d_in[7];    // [3,128,128]
  const float* b_conv    = (const float*)d_in[8];    // [3,128]
  const float* W_head    = (const float*)d_in[9];
  const float* b_head    = (const float*)d_in[10];
  const float* gamma     = (const float*)d_in[11];
  const float* beta      = (const float*)d_in[12];
  float* out = (float*)d_out;

  // ---- workspace layout (~136.2 MB) ----
  size_t S = (size_t)N * H;                  // 12.8M floats = 51.2 MB
  float*   h       = (float*)d_ws;           // 51.2 MB
  uint4*   csr_a16 = (uint4*)(h + S);        // 51.2 MB (E x 32B)
  __half*  h16     = (__half*)(csr_a16 + 2 * (size_t)E);  // 25.6 MB
  int*     csr_src = (int*)(h16 + S);        // 6.4 MB
  int*     deg     = csr_src + E;
  int*     excl    = deg + N;
  int*     rowptr  = excl + N;
  int*     cursor  = rowptr + N;
  int*     bsum    = cursor + N;
  int*     boff    = bsum + 512;
  float*   sum     = out;                    // d_out doubles as layer scratch

  const int eb = (E + 255) / 256;            // 6250

  // ---- CSR build (once; graph fixed across layers) ----
  k_zero<<<NB, 256, 0, stream>>>(deg, N);
  k_hist<<<eb, 256, 0, stream>>>(eidx, deg);
  k_scan_block<<<NB, 256, 0, stream>>>(deg, excl, bsum);
  k_scan_top<<<1, 512, 0, stream>>>(bsum, boff);
  k_scan_add<<<NB, 256, 0, stream>>>(excl, boff, rowptr, cursor);
  k_scatter<<<eb, 256, 0, stream>>>(eidx, edge_attr, cursor, csr_src, csr_a16);

  // ---- network ----
  k_node_linear<<<N / 32, 256, 0, stream>>>(x, W_node, b_node, h, h16);

  for (int l = 0; l < 3; ++l) {
    k_gather<<<N / 4, 256, 0, stream>>>(rowptr, deg, csr_src, csr_a16,
                                        (const __half2*)h16, W_edge, b_edge, h, sum);
    k_node_update<<<N / 32, 256, 0, stream>>>(
        sum, W_conv + (size_t)l * H * H, b_conv + (size_t)l * H, h, h16);
  }

  k_head<<<N / 32, 256, 0, stream>>>(x, W_node, b_node, h, W_head, b_head, gamma, beta, out);
}

// Round 2
// 807.714 us; speedup vs baseline: 1.4681x; 1.1579x over previous
//
#include <hip/hip_runtime.h>
#include <hip/hip_fp16.h>

// GraphEncoder: node linear; 3x GINEConv(eps=0, nn=Linear+LeakyReLU); skip; head Linear+LayerNorm.
// R10: dense GEMMs (node_update x3, head) moved to v_mfma_f32_16x16x32_f16 with Markidis hi/lo
//      split (3 MFMAs: ah*Wh + al*Wh + ah*Wl) so precision matches the old fp32 path (~2e-5 extra).
//      Producers emit exact fp16 hi/lo pairs: gather writes sum_hi/lo (into d_out, same bytes as
//      old fp32 sum); update writes h_hi/h_lo; node_linear writes skip_hi (saved, so head no
//      longer recomputes x@W_node). Weights pre-packed once into MFMA B-frag layout.
//      MFMA mapping used (gfx950, HW-verified C/D): A row=lane&15, k=(lane>>4)*8+e;
//      B col=lane&15, same k-grouping; C/D col=lane&15, row=(lane>>4)*4+reg.
// edge_index arrives as int32 (harness converts int64 inputs).
constexpr int N      = 100000;
constexpr int E      = 1600000;
constexpr int F_IN   = 64;
constexpr int F_EDGE = 16;
constexpr int H      = 128;
constexpr int NB     = (N + 255) / 256;     // 391 scan blocks
constexpr int NBM    = (N + 63) / 64;       // 1563 MFMA blocks (64 rows each)
constexpr float NEG  = 0.01f;
constexpr float EPS  = 1e-5f;

typedef _Float16 hv2  __attribute__((ext_vector_type(2)));
typedef _Float16 f16x8 __attribute__((ext_vector_type(8)));
typedef float    f32x4 __attribute__((ext_vector_type(4)));

// ================= CSR build =================
__global__ __launch_bounds__(256) void k_zero(int* __restrict__ p, int n) {
  int i = blockIdx.x * 256 + threadIdx.x;
  if (i < n) p[i] = 0;
}

__global__ __launch_bounds__(256) void k_hist(const int* __restrict__ eidx, int* __restrict__ deg) {
  int i = blockIdx.x * 256 + threadIdx.x;
  if (i < E) atomicAdd(&deg[eidx[E + i]], 1);
}

__global__ __launch_bounds__(256) void k_scan_block(const int* __restrict__ deg,
    int* __restrict__ excl, int* __restrict__ bsum) {
  __shared__ int s[256];
  int t = threadIdx.x, i = blockIdx.x * 256 + t;
  int v = (i < N) ? deg[i] : 0;
  s[t] = v; __syncthreads();
#pragma unroll
  for (int off = 1; off < 256; off <<= 1) {
    int u = (t >= off) ? s[t - off] : 0;
    __syncthreads();
    s[t] += u;
    __syncthreads();
  }
  if (i < N) excl[i] = s[t] - v;
  if (t == 255) bsum[blockIdx.x] = s[255];
}

__global__ __launch_bounds__(512) void k_scan_top(const int* __restrict__ bsum, int* __restrict__ boff) {
  __shared__ int s[512];
  int t = threadIdx.x;
  int v = (t < NB) ? bsum[t] : 0;
  s[t] = v; __syncthreads();
#pragma unroll
  for (int off = 1; off < 512; off <<= 1) {
    int u = (t >= off) ? s[t - off] : 0;
    __syncthreads();
    s[t] += u;
    __syncthreads();
  }
  if (t < NB) boff[t] = s[t] - v;
}

__global__ __launch_bounds__(256) void k_scan_add(const int* __restrict__ excl,
    const int* __restrict__ boff, int* __restrict__ rowptr, int* __restrict__ cursor) {
  int i = blockIdx.x * 256 + threadIdx.x;
  if (i < N) {
    int r = excl[i] + boff[i >> 8];
    rowptr[i] = r;
    cursor[i] = r;
  }
}

// scatter: CSR-slot src index + edge_attr row converted to fp16 (2x uint4 = 32B/edge)
__global__ __launch_bounds__(256) void k_scatter(const int* __restrict__ eidx,
    const float* __restrict__ edge_attr, int* __restrict__ cursor,
    int* __restrict__ csr_src, uint4* __restrict__ csr_a16) {
  int i = blockIdx.x * 256 + threadIdx.x;
  if (i >= E) return;
  int d = eidx[E + i];
  int pos = atomicAdd(&cursor[d], 1);
  csr_src[pos] = eidx[i];
  const float4* ar = (const float4*)(edge_attr + (size_t)i * F_EDGE);
  float4 f0 = ar[0], f1 = ar[1], f2 = ar[2], f3 = ar[3];
  __half2 hh[8];
  hh[0] = __float22half2_rn(make_float2(f0.x, f0.y));
  hh[1] = __float22half2_rn(make_float2(f0.z, f0.w));
  hh[2] = __float22half2_rn(make_float2(f1.x, f1.y));
  hh[3] = __float22half2_rn(make_float2(f1.z, f1.w));
  hh[4] = __float22half2_rn(make_float2(f2.x, f2.y));
  hh[5] = __float22half2_rn(make_float2(f2.z, f2.w));
  hh[6] = __float22half2_rn(make_float2(f3.x, f3.y));
  hh[7] = __float22half2_rn(make_float2(f3.z, f3.w));
  const uint4* u = (const uint4*)hh;
  csr_a16[2 * (size_t)pos + 0] = u[0];
  csr_a16[2 * (size_t)pos + 1] = u[1];
}

// ================= weight pack: W[128][128] fp32 -> MFMA B-frag fp16 hi/lo =================
// frag (ks,ct): lane l, elem e holds W[ks*32 + (l>>4)*8 + e][ct*16 + (l&15)].
// linear half index = ((ks*8+ct)*64 + lane)*8 + e. mats: 0..2 = W_conv[l], 3 = W_head.
__global__ __launch_bounds__(256) void k_pack_w(
    const float* __restrict__ W_conv, const float* __restrict__ W_head,
    __half* __restrict__ Wp_hi, __half* __restrict__ Wp_lo) {
  int t = blockIdx.x * 256 + threadIdx.x;     // [0, 4*16384)
  int mat = t >> 14;
  int r = t & 16383;
  int e = r & 7, lane = (r >> 3) & 63, ct = (r >> 9) & 7, ks = (r >> 12) & 3;
  int k = ks * 32 + (lane >> 4) * 8 + e;
  int col = ct * 16 + (lane & 15);
  const float* src = (mat < 3) ? (W_conv + (size_t)mat * H * H) : W_head;
  float v = src[k * H + col];
  __half hi = __float2half(v);
  __half lo = __float2half(v - __half2float(hi));
  Wp_hi[t] = hi;
  Wp_lo[t] = lo;
}

// ================= node linear: skip = x @ W_node + b  (32 nodes/block, 4n x 4c per thread) =================
// skip is kept for layer-0 gather (self+neighbors) and the head (no recompute). |skip|~1 so a
// single fp16 copy is enough (ulp/2 ~ 5e-4 vs passing absmax 1.6e-2).
__global__ __launch_bounds__(256) void k_node_linear(
    const float* __restrict__ x, const float* __restrict__ W,
    const float* __restrict__ b, __half* __restrict__ skip_hi) {
  __shared__ float xs[32][F_IN];             // 8 KB
  int i0 = blockIdx.x * 32;
  {
    const float4* s4 = (const float4*)(x + (size_t)i0 * F_IN);
    float4* t4 = (float4*)xs;
#pragma unroll
    for (int r = 0; r < 2; ++r) t4[threadIdx.x + 256 * r] = s4[threadIdx.x + 256 * r];
  }
  __syncthreads();
  int c0 = (threadIdx.x & 31) * 4;
  int n0 = (threadIdx.x >> 5) * 4;
  float4 bb = *(const float4*)(b + c0);
  float4 acc[4] = {bb, bb, bb, bb};
#pragma unroll 4
  for (int k = 0; k < F_IN; ++k) {
    float4 w4 = *(const float4*)(W + k * H + c0);   // coalesced; reused by 4 nodes
#pragma unroll
    for (int j = 0; j < 4; ++j) {
      float s = xs[n0 + j][k];                      // LDS broadcast
      acc[j].x = fmaf(s, w4.x, acc[j].x);
      acc[j].y = fmaf(s, w4.y, acc[j].y);
      acc[j].z = fmaf(s, w4.z, acc[j].z);
      acc[j].w = fmaf(s, w4.w, acc[j].w);
    }
  }
#pragma unroll
  for (int j = 0; j < 4; ++j) {
    size_t idx = (size_t)(i0 + n0 + j) * H + c0;
    __half2* ph = (__half2*)(skip_hi + idx);
    ph[0] = __float22half2_rn(make_float2(acc[j].x, acc[j].y));
    ph[1] = __float22half2_rn(make_float2(acc[j].z, acc[j].w));
  }
}

// ================= gather: sum[i] = self[i] + sum_in relu(nbr16[src] + a16@We + be) =================
// 1 wave per node; lane owns channels {2*lane, 2*lane+1}; scalarized CSR stream (R9);
// output written as exact fp16 hi/lo pair for the MFMA consumer.
__device__ __forceinline__ void dot16(uint4 A0, uint4 A1,
                                      const hv2* __restrict__ wA, const hv2* __restrict__ wB,
                                      float& tx, float& ty) {
  unsigned u[8] = {A0.x, A0.y, A0.z, A0.w, A1.x, A1.y, A1.z, A1.w};
#pragma unroll
  for (int j = 0; j < 8; ++j) {
    hv2 a = __builtin_bit_cast(hv2, u[j]);
    tx = __builtin_amdgcn_fdot2(a, wA[j], tx, false);
    ty = __builtin_amdgcn_fdot2(a, wB[j], ty, false);
  }
}

__global__ __launch_bounds__(256) void k_gather(
    const int* __restrict__ rowptr, const int* __restrict__ deg,
    const int* __restrict__ csr_src, const uint4* __restrict__ csr_a16,
    const __half2* __restrict__ nbr, const float* __restrict__ We,
    const float* __restrict__ be,
    const __half2* __restrict__ self_hi, const __half2* __restrict__ self_lo,
    __half2* __restrict__ sum_hi, __half2* __restrict__ sum_lo) {
  int lane = threadIdx.x & 63;
  int node = (blockIdx.x * 256 + threadIdx.x) >> 6;
  if (node >= N) return;
  int c0 = 2 * lane;
  hv2 wA[8], wB[8];                          // We columns c0,c0+1 packed as k-pairs
#pragma unroll
  for (int j = 0; j < 8; ++j) {
    hv2 a, bq;
    a[0]  = (_Float16)We[(2 * j) * H + c0];
    a[1]  = (_Float16)We[(2 * j + 1) * H + c0];
    bq[0] = (_Float16)We[(2 * j) * H + c0 + 1];
    bq[1] = (_Float16)We[(2 * j + 1) * H + c0 + 1];
    wA[j] = a; wB[j] = bq;
  }
  float2 bias = ((const float2*)be)[lane];
  // self term: hi (+ lo when present) -> fp32
  float2 acc;
  {
    float2 a = __half22float2(self_hi[(size_t)node * 64 + lane]);
    if (self_lo) {                           // wave-uniform scalar branch
      float2 l = __half22float2(self_lo[(size_t)node * 64 + lane]);
      a.x += l.x; a.y += l.y;
    }
    acc = a;
  }
  int p    = __builtin_amdgcn_readfirstlane(rowptr[node]);
  int dg   = __builtin_amdgcn_readfirstlane(deg[node]);
  int pend = p + dg;
  for (; p + 4 <= pend; p += 4) {
    int s0 = csr_src[p + 0];
    int s1 = csr_src[p + 1];
    int s2 = csr_src[p + 2];
    int s3 = csr_src[p + 3];
    __half2 g0 = nbr[(size_t)s0 * 64 + lane];   // 4 independent random 256B/wave gathers
    __half2 g1 = nbr[(size_t)s1 * 64 + lane];
    __half2 g2 = nbr[(size_t)s2 * 64 + lane];
    __half2 g3 = nbr[(size_t)s3 * 64 + lane];
    uint4 A0 = csr_a16[2 * (size_t)p + 0];      // wave-uniform sequential stream (scalar path)
    uint4 A1 = csr_a16[2 * (size_t)p + 1];
    uint4 B0 = csr_a16[2 * (size_t)p + 2];
    uint4 B1 = csr_a16[2 * (size_t)p + 3];
    uint4 C0 = csr_a16[2 * (size_t)p + 4];
    uint4 C1 = csr_a16[2 * (size_t)p + 5];
    uint4 D0 = csr_a16[2 * (size_t)p + 6];
    uint4 D1 = csr_a16[2 * (size_t)p + 7];
    float t0x = bias.x, t0y = bias.y;
    float t1x = bias.x, t1y = bias.y;
    float t2x = bias.x, t2y = bias.y;
    float t3x = bias.x, t3y = bias.y;
    dot16(A0, A1, wA, wB, t0x, t0y);
    dot16(B0, B1, wA, wB, t1x, t1y);
    dot16(C0, C1, wA, wB, t2x, t2y);
    dot16(D0, D1, wA, wB, t3x, t3y);
    float2 f0 = __half22float2(g0);
    float2 f1 = __half22float2(g1);
    float2 f2 = __half22float2(g2);
    float2 f3 = __half22float2(g3);
    acc.x += fmaxf(f0.x + t0x, 0.f) + fmaxf(f1.x + t1x, 0.f)
           + fmaxf(f2.x + t2x, 0.f) + fmaxf(f3.x + t3x, 0.f);
    acc.y += fmaxf(f0.y + t0y, 0.f) + fmaxf(f1.y + t1y, 0.f)
           + fmaxf(f2.y + t2y, 0.f) + fmaxf(f3.y + t3y, 0.f);
  }
  for (; p + 2 <= pend; p += 2) {
    int s0 = csr_src[p];
    int s1 = csr_src[p + 1];
    __half2 g0 = nbr[(size_t)s0 * 64 + lane];
    __half2 g1 = nbr[(size_t)s1 * 64 + lane];
    uint4 A0 = csr_a16[2 * (size_t)p + 0];
    uint4 A1 = csr_a16[2 * (size_t)p + 1];
    uint4 B0 = csr_a16[2 * (size_t)p + 2];
    uint4 B1 = csr_a16[2 * (size_t)p + 3];
    float t0x = bias.x, t0y = bias.y;
    float t1x = bias.x, t1y = bias.y;
    dot16(A0, A1, wA, wB, t0x, t0y);
    dot16(B0, B1, wA, wB, t1x, t1y);
    float2 gf0 = __half22float2(g0);
    float2 gf1 = __half22float2(g1);
    acc.x += fmaxf(gf0.x + t0x, 0.f) + fmaxf(gf1.x + t1x, 0.f);
    acc.y += fmaxf(gf0.y + t0y, 0.f) + fmaxf(gf1.y + t1y, 0.f);
  }
  for (; p < pend; ++p) {
    int s = csr_src[p];
    __half2 g = nbr[(size_t)s * 64 + lane];
    uint4 A0 = csr_a16[2 * (size_t)p + 0];
    uint4 A1 = csr_a16[2 * (size_t)p + 1];
    float tx = bias.x, ty = bias.y;
    dot16(A0, A1, wA, wB, tx, ty);
    float2 gf = __half22float2(g);
    acc.x += fmaxf(gf.x + tx, 0.f);
    acc.y += fmaxf(gf.y + ty, 0.f);
  }
  // exact hi/lo split
  __half2 hh = __float22half2_rn(acc);
  float2 rf = __half22float2(hh);
  __half2 hl = __float22half2_rn(make_float2(acc.x - rf.x, acc.y - rf.y));
  sum_hi[(size_t)node * 64 + lane] = hh;
  sum_lo[(size_t)node * 64 + lane] = hl;
}

// ================= node update (MFMA): h = leaky_relu(sum @ W + b), hi/lo in, hi/lo out =================
// 4 waves/block, each wave one 16-row strip (64 rows/block). acc = Ah*Wh + Al*Wh + Ah*Wl.
__global__ __launch_bounds__(256) void k_update_mfma(
    const __half* __restrict__ Ahi, const __half* __restrict__ Alo,
    const uint4* __restrict__ Wph, const uint4* __restrict__ Wpl,
    const float* __restrict__ b,
    __half* __restrict__ Ohi, __half* __restrict__ Olo) {
  int lane = threadIdx.x & 63;
  int wv = threadIdx.x >> 6;
  int rowbase = blockIdx.x * 64 + wv * 16;
  int arow = rowbase + (lane & 15);
  if (arow >= N) arow = N - 1;
  int kg = lane >> 4;
  const uint4* pa_hi = (const uint4*)(Ahi + (size_t)arow * H);
  const uint4* pa_lo = (const uint4*)(Alo + (size_t)arow * H);
  f16x8 a_hi[4], a_lo[4];
#pragma unroll
  for (int ks = 0; ks < 4; ++ks) {
    a_hi[ks] = __builtin_bit_cast(f16x8, pa_hi[ks * 4 + kg]);
    a_lo[ks] = __builtin_bit_cast(f16x8, pa_lo[ks * 4 + kg]);
  }
  f32x4 acc[8];
#pragma unroll
  for (int ct = 0; ct < 8; ++ct) acc[ct] = {0.f, 0.f, 0.f, 0.f};
#pragma unroll
  for (int ct = 0; ct < 8; ++ct) {
#pragma unroll
    for (int ks = 0; ks < 4; ++ks) {
      f16x8 bh = __builtin_bit_cast(f16x8, Wph[(ks * 8 + ct) * 64 + lane]);
      f16x8 bl = __builtin_bit_cast(f16x8, Wpl[(ks * 8 + ct) * 64 + lane]);
      acc[ct] = __builtin_amdgcn_mfma_f32_16x16x32_f16(a_hi[ks], bh, acc[ct], 0, 0, 0);
      acc[ct] = __builtin_amdgcn_mfma_f32_16x16x32_f16(a_lo[ks], bh, acc[ct], 0, 0, 0);
      acc[ct] = __builtin_amdgcn_mfma_f32_16x16x32_f16(a_hi[ks], bl, acc[ct], 0, 0, 0);
    }
  }
  int colb = lane & 15;
#pragma unroll
  for (int ct = 0; ct < 8; ++ct) {
    float bias = b[ct * 16 + colb];
#pragma unroll
    for (int r = 0; r < 4; ++r) {
      int grow = rowbase + kg * 4 + r;
      if (grow < N) {
        float y = acc[ct][r] + bias;
        y = y >= 0.f ? y : NEG * y;
        __half hi = __float2half(y);
        __half lo = __float2half(y - __half2float(hi));
        Ohi[(size_t)grow * H + ct * 16 + colb] = hi;
        Olo[(size_t)grow * H + ct * 16 + colb] = lo;
      }
    }
  }
}

// ================= head (MFMA): t = skip + hfin; y = t @ W_head + b; LayerNorm =================
__global__ __launch_bounds__(256) void k_head_mfma(
    const __half* __restrict__ Shi, const __half* __restrict__ Hhi,
    const __half* __restrict__ Hlo,
    const uint4* __restrict__ Wph, const uint4* __restrict__ Wpl,
    const float* __restrict__ b, const float* __restrict__ gamma,
    const float* __restrict__ beta, float* __restrict__ out) {
  int lane = threadIdx.x & 63;
  int wv = threadIdx.x >> 6;
  int rowbase = blockIdx.x * 64 + wv * 16;
  int arow = rowbase + (lane & 15);
  if (arow >= N) arow = N - 1;
  int kg = lane >> 4;
  const uint4* ps = (const uint4*)(Shi + (size_t)arow * H);
  const uint4* ph = (const uint4*)(Hhi + (size_t)arow * H);
  const uint4* pl = (const uint4*)(Hlo + (size_t)arow * H);
  f16x8 a_hi[4], a_lo[4];
#pragma unroll
  for (int ks = 0; ks < 4; ++ks) {
    f16x8 s8 = __builtin_bit_cast(f16x8, ps[ks * 4 + kg]);
    f16x8 h8 = __builtin_bit_cast(f16x8, ph[ks * 4 + kg]);
    f16x8 l8 = __builtin_bit_cast(f16x8, pl[ks * 4 + kg]);
    f16x8 th, tl;
#pragma unroll
    for (int e = 0; e < 8; ++e) {
      float t = (float)s8[e] + (float)h8[e] + (float)l8[e];
      _Float16 hi = (_Float16)t;
      th[e] = hi;
      tl[e] = (_Float16)(t - (float)hi);
    }
    a_hi[ks] = th;
    a_lo[ks] = tl;
  }
  f32x4 acc[8];
#pragma unroll
  for (int ct = 0; ct < 8; ++ct) acc[ct] = {0.f, 0.f, 0.f, 0.f};
#pragma unroll
  for (int ct = 0; ct < 8; ++ct) {
#pragma unroll
    for (int ks = 0; ks < 4; ++ks) {
      f16x8 bh = __builtin_bit_cast(f16x8, Wph[(ks * 8 + ct) * 64 + lane]);
      f16x8 bl = __builtin_bit_cast(f16x8, Wpl[(ks * 8 + ct) * 64 + lane]);
      acc[ct] = __builtin_amdgcn_mfma_f32_16x16x32_f16(a_hi[ks], bh, acc[ct], 0, 0, 0);
      acc[ct] = __builtin_amdgcn_mfma_f32_16x16x32_f16(a_lo[ks], bh, acc[ct], 0, 0, 0);
      acc[ct] = __builtin_amdgcn_mfma_f32_16x16x32_f16(a_hi[ks], bl, acc[ct], 0, 0, 0);
    }
  }
  // LayerNorm epilogue: row r of this tile lives in acc[ct][r] across the 16 lanes of group kg.
  int colb = lane & 15;
  float bias[8], gam[8], bet[8];
#pragma unroll
  for (int ct = 0; ct < 8; ++ct) {
    bias[ct] = b[ct * 16 + colb];
    gam[ct]  = gamma[ct * 16 + colb];
    bet[ct]  = beta[ct * 16 + colb];
  }
#pragma unroll
  for (int r = 0; r < 4; ++r) {
    float vals[8];
    float S = 0.f, S2 = 0.f;
#pragma unroll
    for (int ct = 0; ct < 8; ++ct) {
      float v = acc[ct][r] + bias[ct];
      vals[ct] = v;
      S += v;
      S2 += v * v;
    }
#pragma unroll
    for (int off = 1; off < 16; off <<= 1) {   // reduce across the 16 lanes sharing this row
      S  += __shfl_xor(S, off);
      S2 += __shfl_xor(S2, off);
    }
    float mu  = S * (1.f / H);
    float var = S2 * (1.f / H) - mu * mu;
    float inv = rsqrtf(var + EPS);
    int grow = rowbase + kg * 4 + r;
    if (grow < N) {
#pragma unroll
      for (int ct = 0; ct < 8; ++ct)
        out[(size_t)grow * H + ct * 16 + colb] = (vals[ct] - mu) * inv * gam[ct] + bet[ct];
    }
  }
}

extern "C" void kernel_launch(void* const* d_in, const int* in_sizes, int n_in,
                              void* d_out, int out_size, void* d_ws, size_t ws_size,
                              hipStream_t stream) {
  const float* x         = (const float*)d_in[0];
  const float* edge_attr = (const float*)d_in[1];
  const int*   eidx      = (const int*)d_in[2];      // int32 (harness-converted)
  const float* W_node    = (const float*)d_in[3];
  const float* b_node    = (const float*)d_in[4];
  const float* W_edge    = (const float*)d_in[5];
  const float* b_edge    = (const float*)d_in[6];
  const float* W_conv    = (const float*)d_in[7];    // [3,128,128]
  const float* b_conv    = (const float*)d_in[8];    // [3,128]
  const float* W_head    = (const float*)d_in[9];
  const float* b_head    = (const float*)d_in[10];
  const float* gamma     = (const float*)d_in[11];
  const float* beta      = (const float*)d_in[12];
  float* out = (float*)d_out;

  // ---- workspace layout (~136.3 MB) ----
  size_t S = (size_t)N * H;                  // 12.8M elems
  __half* h_hi    = (__half*)d_ws;           // 25.6 MB
  __half* h_lo    = h_hi + S;                // 25.6 MB
  __half* skip_hi = h_lo + S;                // 25.6 MB
  uint4*  csr_a16 = (uint4*)(skip_hi + S);   // 51.2 MB (E x 32B)
  int*    csr_src = (int*)(csr_a16 + 2 * (size_t)E);  // 6.4 MB
  int*    deg     = csr_src + E;
  int*    excl    = deg + N;
  int*    rowptr  = excl + N;
  int*    cursor  = rowptr + N;
  int*    bsum    = cursor + N;
  int*    boff    = bsum + 512;
  __half* Wp_hi   = (__half*)(boff + 512);   // 4 mats x 16384 halfs = 128 KB
  __half* Wp_lo   = Wp_hi + 4 * 16384;       // 128 KB
  __half* sum_hi  = (__half*)out;            // d_out doubles as layer scratch (hi/lo halves)
  __half* sum_lo  = sum_hi + S;

  const int eb = (E + 255) / 256;            // 6250

  // ---- weight pack + CSR build (once) ----
  k_pack_w<<<256, 256, 0, stream>>>(W_conv, W_head, Wp_hi, Wp_lo);
  k_zero<<<NB, 256, 0, stream>>>(deg, N);
  k_hist<<<eb, 256, 0, stream>>>(eidx, deg);
  k_scan_block<<<NB, 256, 0, stream>>>(deg, excl, bsum);
  k_scan_top<<<1, 512, 0, stream>>>(bsum, boff);
  k_scan_add<<<NB, 256, 0, stream>>>(excl, boff, rowptr, cursor);
  k_scatter<<<eb, 256, 0, stream>>>(eidx, edge_attr, cursor, csr_src, csr_a16);

  // ---- network ----
  k_node_linear<<<N / 32, 256, 0, stream>>>(x, W_node, b_node, skip_hi);

  for (int l = 0; l < 3; ++l) {
    const __half* selfh = (l == 0) ? skip_hi : h_hi;
    const __half* selfl = (l == 0) ? nullptr : h_lo;
    const __half* nbr   = (l == 0) ? skip_hi : h_hi;
    k_gather<<<N / 4, 256, 0, stream>>>(rowptr, deg, csr_src, csr_a16,
                                        (const __half2*)nbr, W_edge, b_edge,
                                        (const __half2*)selfh, (const __half2*)selfl,
                                        (__half2*)sum_hi, (__half2*)sum_lo);
    k_update_mfma<<<NBM, 256, 0, stream>>>(
        sum_hi, sum_lo,
        (const uint4*)(Wp_hi + (size_t)l * 16384), (const uint4*)(Wp_lo + (size_t)l * 16384),
        b_conv + (size_t)l * H, h_hi, h_lo);
  }

  k_head_mfma<<<NBM, 256, 0, stream>>>(
      skip_hi, h_hi, h_lo,
      (const uint4*)(Wp_hi + 3 * (size_t)16384), (const uint4*)(Wp_lo + 3 * (size_t)16384),
      b_head, gamma, beta, out);
}

// Round 5
// 783.676 us; speedup vs baseline: 1.5131x; 1.0307x over previous
//
#include <hip/hip_runtime.h>
#include <hip/hip_fp16.h>

// GraphEncoder: node linear; 3x GINEConv(eps=0, nn=Linear+LeakyReLU); skip; head Linear+LayerNorm.
// R13: R12's identical-absmax fail (0.078125, same as R11) falsified the node-linear theory; the
//      shared delta was the column remap, whose ONLY arithmetic change is the LayerNorm reduction
//      order in k_head_mfma (per-lane partials now group different columns -> different fp32
//      rounding -> one bf16-boundary element flips = +0.0625). GEMM elements themselves are
//      bit-identical under the remap. Fix: keep the coalesced remap for the 3 k_update_mfma
//      layers (pure perf, bit-identical), restore k_head_mfma VERBATIM from R10 (pack mat3 in the
//      R10 layout col=ct*16+(lane&15)) so the final output is bit-identical to R10's pass.
// edge_index arrives as int32 (harness converts int64 inputs).
constexpr int N      = 100000;
constexpr int E      = 1600000;
constexpr int F_IN   = 64;
constexpr int F_EDGE = 16;
constexpr int H      = 128;
constexpr int NB     = (N + 255) / 256;     // 391 scan blocks
constexpr int NBM    = (N + 63) / 64;       // 1563 MFMA blocks (64 rows each)
constexpr float NEG  = 0.01f;
constexpr float EPS  = 1e-5f;

typedef _Float16 hv2   __attribute__((ext_vector_type(2)));
typedef _Float16 f16x8 __attribute__((ext_vector_type(8)));
typedef float    f32x4 __attribute__((ext_vector_type(4)));

// ================= CSR build =================
__global__ __launch_bounds__(256) void k_zero(int* __restrict__ p, int n) {
  int i = blockIdx.x * 256 + threadIdx.x;
  if (i < n) p[i] = 0;
}

__global__ __launch_bounds__(256) void k_hist(const int* __restrict__ eidx, int* __restrict__ deg) {
  int i = blockIdx.x * 256 + threadIdx.x;
  if (i < E) atomicAdd(&deg[eidx[E + i]], 1);
}

__global__ __launch_bounds__(256) void k_scan_block(const int* __restrict__ deg,
    int* __restrict__ excl, int* __restrict__ bsum) {
  __shared__ int s[256];
  int t = threadIdx.x, i = blockIdx.x * 256 + t;
  int v = (i < N) ? deg[i] : 0;
  s[t] = v; __syncthreads();
#pragma unroll
  for (int off = 1; off < 256; off <<= 1) {
    int u = (t >= off) ? s[t - off] : 0;
    __syncthreads();
    s[t] += u;
    __syncthreads();
  }
  if (i < N) excl[i] = s[t] - v;
  if (t == 255) bsum[blockIdx.x] = s[255];
}

__global__ __launch_bounds__(512) void k_scan_top(const int* __restrict__ bsum, int* __restrict__ boff) {
  __shared__ int s[512];
  int t = threadIdx.x;
  int v = (t < NB) ? bsum[t] : 0;
  s[t] = v; __syncthreads();
#pragma unroll
  for (int off = 1; off < 512; off <<= 1) {
    int u = (t >= off) ? s[t - off] : 0;
    __syncthreads();
    s[t] += u;
    __syncthreads();
  }
  if (t < NB) boff[t] = s[t] - v;
}

__global__ __launch_bounds__(256) void k_scan_add(const int* __restrict__ excl,
    const int* __restrict__ boff, int* __restrict__ rowptr, int* __restrict__ cursor) {
  int i = blockIdx.x * 256 + threadIdx.x;
  if (i < N) {
    int r = excl[i] + boff[i >> 8];
    rowptr[i] = r;
    cursor[i] = r;
  }
}

// scatter: CSR-slot src index + edge_attr row converted to fp16 (2x uint4 = 32B/edge)
__global__ __launch_bounds__(256) void k_scatter(const int* __restrict__ eidx,
    const float* __restrict__ edge_attr, int* __restrict__ cursor,
    int* __restrict__ csr_src, uint4* __restrict__ csr_a16) {
  int i = blockIdx.x * 256 + threadIdx.x;
  if (i >= E) return;
  int d = eidx[E + i];
  int pos = atomicAdd(&cursor[d], 1);
  csr_src[pos] = eidx[i];
  const float4* ar = (const float4*)(edge_attr + (size_t)i * F_EDGE);
  float4 f0 = ar[0], f1 = ar[1], f2 = ar[2], f3 = ar[3];
  __half2 hh[8];
  hh[0] = __float22half2_rn(make_float2(f0.x, f0.y));
  hh[1] = __float22half2_rn(make_float2(f0.z, f0.w));
  hh[2] = __float22half2_rn(make_float2(f1.x, f1.y));
  hh[3] = __float22half2_rn(make_float2(f1.z, f1.w));
  hh[4] = __float22half2_rn(make_float2(f2.x, f2.y));
  hh[5] = __float22half2_rn(make_float2(f2.z, f2.w));
  hh[6] = __float22half2_rn(make_float2(f3.x, f3.y));
  hh[7] = __float22half2_rn(make_float2(f3.z, f3.w));
  const uint4* u = (const uint4*)hh;
  csr_a16[2 * (size_t)pos + 0] = u[0];
  csr_a16[2 * (size_t)pos + 1] = u[1];
}

// ================= weight pack -> MFMA B-frag fp16 hi/lo =================
// mats 0..2 (W_conv[l]): NEW layout, element = W[ks*32+(lane>>4)*8+e][(lane&15)*8 + ct]
//   (coalesced epilogue: lane owns 8 consecutive cols).
// mat 3 (W_head): R10 layout, element = W[ks*32+(lane>>4)*8+e][ct*16 + (lane&15)]
//   (k_head_mfma is the R10 kernel verbatim -> LN order bit-identical to the passing run).
// half index = ((ks*8+ct)*64 + lane)*8 + e.
__global__ __launch_bounds__(256) void k_pack_w(
    const float* __restrict__ W_conv, const float* __restrict__ W_head,
    __half* __restrict__ Wp_hi, __half* __restrict__ Wp_lo) {
  int t = blockIdx.x * 256 + threadIdx.x;     // [0, 4*16384)
  int mat = t >> 14;
  int r = t & 16383;
  int e = r & 7, lane = (r >> 3) & 63, ct = (r >> 9) & 7, ks = (r >> 12) & 3;
  int k = ks * 32 + (lane >> 4) * 8 + e;
  int col = (mat < 3) ? ((lane & 15) * 8 + ct) : (ct * 16 + (lane & 15));
  const float* src = (mat < 3) ? (W_conv + (size_t)mat * H * H) : W_head;
  float v = src[k * H + col];
  __half hi = __float2half(v);
  __half lo = __float2half(v - __half2float(hi));
  Wp_hi[t] = hi;
  Wp_lo[t] = lo;
}

// ================= node linear (fp32, R10 lineage): skip = x @ W_node + b, fp16 hi out =================
__global__ __launch_bounds__(256) void k_node_linear(
    const float* __restrict__ x, const float* __restrict__ W,
    const float* __restrict__ b, __half* __restrict__ skip_hi) {
  __shared__ float xs[32][F_IN];             // 8 KB
  int i0 = blockIdx.x * 32;
  {
    const float4* s4 = (const float4*)(x + (size_t)i0 * F_IN);
    float4* t4 = (float4*)xs;
#pragma unroll
    for (int r = 0; r < 2; ++r) t4[threadIdx.x + 256 * r] = s4[threadIdx.x + 256 * r];
  }
  __syncthreads();
  int c0 = (threadIdx.x & 31) * 4;
  int n0 = (threadIdx.x >> 5) * 4;
  float4 bb = *(const float4*)(b + c0);
  float4 acc[4] = {bb, bb, bb, bb};
#pragma unroll 4
  for (int k = 0; k < F_IN; ++k) {
    float4 w4 = *(const float4*)(W + k * H + c0);   // coalesced; reused by 4 nodes
#pragma unroll
    for (int j = 0; j < 4; ++j) {
      float s = xs[n0 + j][k];                      // LDS broadcast
      acc[j].x = fmaf(s, w4.x, acc[j].x);
      acc[j].y = fmaf(s, w4.y, acc[j].y);
      acc[j].z = fmaf(s, w4.z, acc[j].z);
      acc[j].w = fmaf(s, w4.w, acc[j].w);
    }
  }
#pragma unroll
  for (int j = 0; j < 4; ++j) {
    size_t idx = (size_t)(i0 + n0 + j) * H + c0;
    __half2* ph = (__half2*)(skip_hi + idx);
    ph[0] = __float22half2_rn(make_float2(acc[j].x, acc[j].y));
    ph[1] = __float22half2_rn(make_float2(acc[j].z, acc[j].w));
  }
}

// ================= gather: sum[i] = self[i] + sum_in relu(nbr16[src] + a16@We + be) =================
__device__ __forceinline__ void dot16(uint4 A0, uint4 A1,
                                      const hv2* __restrict__ wA, const hv2* __restrict__ wB,
                                      float& tx, float& ty) {
  unsigned u[8] = {A0.x, A0.y, A0.z, A0.w, A1.x, A1.y, A1.z, A1.w};
#pragma unroll
  for (int j = 0; j < 8; ++j) {
    hv2 a = __builtin_bit_cast(hv2, u[j]);
    tx = __builtin_amdgcn_fdot2(a, wA[j], tx, false);
    ty = __builtin_amdgcn_fdot2(a, wB[j], ty, false);
  }
}

__global__ __launch_bounds__(256) void k_gather(
    const int* __restrict__ rowptr, const int* __restrict__ deg,
    const int* __restrict__ csr_src, const uint4* __restrict__ csr_a16,
    const __half2* __restrict__ nbr, const float* __restrict__ We,
    const float* __restrict__ be,
    const __half2* __restrict__ self_hi, const __half2* __restrict__ self_lo,
    __half2* __restrict__ sum_hi, __half2* __restrict__ sum_lo) {
  int lane = threadIdx.x & 63;
  int node = (blockIdx.x * 256 + threadIdx.x) >> 6;
  if (node >= N) return;
  int c0 = 2 * lane;
  hv2 wA[8], wB[8];                          // We columns c0,c0+1 packed as k-pairs
#pragma unroll
  for (int j = 0; j < 8; ++j) {
    hv2 a, bq;
    a[0]  = (_Float16)We[(2 * j) * H + c0];
    a[1]  = (_Float16)We[(2 * j + 1) * H + c0];
    bq[0] = (_Float16)We[(2 * j) * H + c0 + 1];
    bq[1] = (_Float16)We[(2 * j + 1) * H + c0 + 1];
    wA[j] = a; wB[j] = bq;
  }
  float2 bias = ((const float2*)be)[lane];
  float2 acc;
  {
    float2 a = __half22float2(self_hi[(size_t)node * 64 + lane]);
    if (self_lo) {                           // wave-uniform scalar branch
      float2 l = __half22float2(self_lo[(size_t)node * 64 + lane]);
      a.x += l.x; a.y += l.y;
    }
    acc = a;
  }
  int p    = __builtin_amdgcn_readfirstlane(rowptr[node]);
  int dg   = __builtin_amdgcn_readfirstlane(deg[node]);
  int pend = p + dg;
  for (; p + 4 <= pend; p += 4) {
    int s0 = csr_src[p + 0];
    int s1 = csr_src[p + 1];
    int s2 = csr_src[p + 2];
    int s3 = csr_src[p + 3];
    __half2 g0 = nbr[(size_t)s0 * 64 + lane];   // 4 independent random 256B/wave gathers
    __half2 g1 = nbr[(size_t)s1 * 64 + lane];
    __half2 g2 = nbr[(size_t)s2 * 64 + lane];
    __half2 g3 = nbr[(size_t)s3 * 64 + lane];
    uint4 A0 = csr_a16[2 * (size_t)p + 0];      // wave-uniform sequential stream (scalar path)
    uint4 A1 = csr_a16[2 * (size_t)p + 1];
    uint4 B0 = csr_a16[2 * (size_t)p + 2];
    uint4 B1 = csr_a16[2 * (size_t)p + 3];
    uint4 C0 = csr_a16[2 * (size_t)p + 4];
    uint4 C1 = csr_a16[2 * (size_t)p + 5];
    uint4 D0 = csr_a16[2 * (size_t)p + 6];
    uint4 D1 = csr_a16[2 * (size_t)p + 7];
    float t0x = bias.x, t0y = bias.y;
    float t1x = bias.x, t1y = bias.y;
    float t2x = bias.x, t2y = bias.y;
    float t3x = bias.x, t3y = bias.y;
    dot16(A0, A1, wA, wB, t0x, t0y);
    dot16(B0, B1, wA, wB, t1x, t1y);
    dot16(C0, C1, wA, wB, t2x, t2y);
    dot16(D0, D1, wA, wB, t3x, t3y);
    float2 f0 = __half22float2(g0);
    float2 f1 = __half22float2(g1);
    float2 f2 = __half22float2(g2);
    float2 f3 = __half22float2(g3);
    acc.x += fmaxf(f0.x + t0x, 0.f) + fmaxf(f1.x + t1x, 0.f)
           + fmaxf(f2.x + t2x, 0.f) + fmaxf(f3.x + t3x, 0.f);
    acc.y += fmaxf(f0.y + t0y, 0.f) + fmaxf(f1.y + t1y, 0.f)
           + fmaxf(f2.y + t2y, 0.f) + fmaxf(f3.y + t3y, 0.f);
  }
  for (; p + 2 <= pend; p += 2) {
    int s0 = csr_src[p];
    int s1 = csr_src[p + 1];
    __half2 g0 = nbr[(size_t)s0 * 64 + lane];
    __half2 g1 = nbr[(size_t)s1 * 64 + lane];
    uint4 A0 = csr_a16[2 * (size_t)p + 0];
    uint4 A1 = csr_a16[2 * (size_t)p + 1];
    uint4 B0 = csr_a16[2 * (size_t)p + 2];
    uint4 B1 = csr_a16[2 * (size_t)p + 3];
    float t0x = bias.x, t0y = bias.y;
    float t1x = bias.x, t1y = bias.y;
    dot16(A0, A1, wA, wB, t0x, t0y);
    dot16(B0, B1, wA, wB, t1x, t1y);
    float2 gf0 = __half22float2(g0);
    float2 gf1 = __half22float2(g1);
    acc.x += fmaxf(gf0.x + t0x, 0.f) + fmaxf(gf1.x + t1x, 0.f);
    acc.y += fmaxf(gf0.y + t0y, 0.f) + fmaxf(gf1.y + t1y, 0.f);
  }
  for (; p < pend; ++p) {
    int s = csr_src[p];
    __half2 g = nbr[(size_t)s * 64 + lane];
    uint4 A0 = csr_a16[2 * (size_t)p + 0];
    uint4 A1 = csr_a16[2 * (size_t)p + 1];
    float tx = bias.x, ty = bias.y;
    dot16(A0, A1, wA, wB, tx, ty);
    float2 gf = __half22float2(g);
    acc.x += fmaxf(gf.x + tx, 0.f);
    acc.y += fmaxf(gf.y + ty, 0.f);
  }
  // exact hi/lo split
  __half2 hh = __float22half2_rn(acc);
  float2 rf = __half22float2(hh);
  __half2 hl = __float22half2_rn(make_float2(acc.x - rf.x, acc.y - rf.y));
  sum_hi[(size_t)node * 64 + lane] = hh;
  sum_lo[(size_t)node * 64 + lane] = hl;
}

// ================= node update (MFMA, coalesced epilogue): h = leaky_relu(sum @ W + b) =================
// 4 waves/block, wave owns a 16-row strip. acc = Ah*Wh + Al*Wh + Ah*Wl.
// NEW B layout: lane owns 8 consecutive output cols (col = colb*8 + ct) -> uint4 stores.
// Per-element arithmetic is bit-identical to the R10 layout (pure coordinate permutation).
__global__ __launch_bounds__(256) void k_update_mfma(
    const __half* __restrict__ Ahi, const __half* __restrict__ Alo,
    const uint4* __restrict__ Wph, const uint4* __restrict__ Wpl,
    const float* __restrict__ b,
    __half* __restrict__ Ohi, __half* __restrict__ Olo) {
  int lane = threadIdx.x & 63;
  int wv = threadIdx.x >> 6;
  int rowbase = blockIdx.x * 64 + wv * 16;
  int arow = rowbase + (lane & 15);
  if (arow >= N) arow = N - 1;
  int kg = lane >> 4;
  const uint4* pa_hi = (const uint4*)(Ahi + (size_t)arow * H);
  const uint4* pa_lo = (const uint4*)(Alo + (size_t)arow * H);
  f16x8 a_hi[4], a_lo[4];
#pragma unroll
  for (int ks = 0; ks < 4; ++ks) {
    a_hi[ks] = __builtin_bit_cast(f16x8, pa_hi[ks * 4 + kg]);
    a_lo[ks] = __builtin_bit_cast(f16x8, pa_lo[ks * 4 + kg]);
  }
  f32x4 acc[8];
#pragma unroll
  for (int ct = 0; ct < 8; ++ct) acc[ct] = {0.f, 0.f, 0.f, 0.f};
#pragma unroll
  for (int ct = 0; ct < 8; ++ct) {
#pragma unroll
    for (int ks = 0; ks < 4; ++ks) {
      f16x8 bh = __builtin_bit_cast(f16x8, Wph[(ks * 8 + ct) * 64 + lane]);
      f16x8 bl = __builtin_bit_cast(f16x8, Wpl[(ks * 8 + ct) * 64 + lane]);
      acc[ct] = __builtin_amdgcn_mfma_f32_16x16x32_f16(a_hi[ks], bh, acc[ct], 0, 0, 0);
      acc[ct] = __builtin_amdgcn_mfma_f32_16x16x32_f16(a_lo[ks], bh, acc[ct], 0, 0, 0);
      acc[ct] = __builtin_amdgcn_mfma_f32_16x16x32_f16(a_hi[ks], bl, acc[ct], 0, 0, 0);
    }
  }
  int colb = lane & 15;
  float4 b0 = *(const float4*)(b + colb * 8);
  float4 b1 = *(const float4*)(b + colb * 8 + 4);
  float bias[8] = {b0.x, b0.y, b0.z, b0.w, b1.x, b1.y, b1.z, b1.w};
#pragma unroll
  for (int r = 0; r < 4; ++r) {
    int grow = rowbase + kg * 4 + r;
    if (grow < N) {
      __half2 hh[4], ll[4];
#pragma unroll
      for (int q = 0; q < 4; ++q) {
        float y0 = acc[2 * q][r] + bias[2 * q];
        float y1 = acc[2 * q + 1][r] + bias[2 * q + 1];
        y0 = y0 >= 0.f ? y0 : NEG * y0;
        y1 = y1 >= 0.f ? y1 : NEG * y1;
        __half2 h2 = __float22half2_rn(make_float2(y0, y1));
        float2 rf = __half22float2(h2);
        hh[q] = h2;
        ll[q] = __float22half2_rn(make_float2(y0 - rf.x, y1 - rf.y));
      }
      *(uint4*)(Ohi + (size_t)grow * H + colb * 8) = *(const uint4*)hh;   // 16B coalesced
      *(uint4*)(Olo + (size_t)grow * H + colb * 8) = *(const uint4*)ll;
    }
  }
}

// ================= head (MFMA, R10 VERBATIM): t = skip + hfin; y = t @ W_head + b; LayerNorm ====
// R10 layout (col=ct*16+colb), R10 LN reduction order, R10 store pattern -> output bit-identical
// to the R10 passing run. Do NOT touch the LN arithmetic order (bf16-boundary cliff).
__global__ __launch_bounds__(256) void k_head_mfma(
    const __half* __restrict__ Shi, const __half* __restrict__ Hhi,
    const __half* __restrict__ Hlo,
    const uint4* __restrict__ Wph, const uint4* __restrict__ Wpl,
    const float* __restrict__ b, const float* __restrict__ gamma,
    const float* __restrict__ beta, float* __restrict__ out) {
  int lane = threadIdx.x & 63;
  int wv = threadIdx.x >> 6;
  int rowbase = blockIdx.x * 64 + wv * 16;
  int arow = rowbase + (lane & 15);
  if (arow >= N) arow = N - 1;
  int kg = lane >> 4;
  const uint4* ps = (const uint4*)(Shi + (size_t)arow * H);
  const uint4* ph = (const uint4*)(Hhi + (size_t)arow * H);
  const uint4* pl = (const uint4*)(Hlo + (size_t)arow * H);
  f16x8 a_hi[4], a_lo[4];
#pragma unroll
  for (int ks = 0; ks < 4; ++ks) {
    f16x8 s8 = __builtin_bit_cast(f16x8, ps[ks * 4 + kg]);
    f16x8 h8 = __builtin_bit_cast(f16x8, ph[ks * 4 + kg]);
    f16x8 l8 = __builtin_bit_cast(f16x8, pl[ks * 4 + kg]);
    f16x8 th, tl;
#pragma unroll
    for (int e = 0; e < 8; ++e) {
      float t = (float)s8[e] + (float)h8[e] + (float)l8[e];
      _Float16 hi = (_Float16)t;
      th[e] = hi;
      tl[e] = (_Float16)(t - (float)hi);
    }
    a_hi[ks] = th;
    a_lo[ks] = tl;
  }
  f32x4 acc[8];
#pragma unroll
  for (int ct = 0; ct < 8; ++ct) acc[ct] = {0.f, 0.f, 0.f, 0.f};
#pragma unroll
  for (int ct = 0; ct < 8; ++ct) {
#pragma unroll
    for (int ks = 0; ks < 4; ++ks) {
      f16x8 bh = __builtin_bit_cast(f16x8, Wph[(ks * 8 + ct) * 64 + lane]);
      f16x8 bl = __builtin_bit_cast(f16x8, Wpl[(ks * 8 + ct) * 64 + lane]);
      acc[ct] = __builtin_amdgcn_mfma_f32_16x16x32_f16(a_hi[ks], bh, acc[ct], 0, 0, 0);
      acc[ct] = __builtin_amdgcn_mfma_f32_16x16x32_f16(a_lo[ks], bh, acc[ct], 0, 0, 0);
      acc[ct] = __builtin_amdgcn_mfma_f32_16x16x32_f16(a_hi[ks], bl, acc[ct], 0, 0, 0);
    }
  }
  // LayerNorm epilogue: row r of this tile lives in acc[ct][r] across the 16 lanes of group kg.
  int colb = lane & 15;
  float bias[8], gam[8], bet[8];
#pragma unroll
  for (int ct = 0; ct < 8; ++ct) {
    bias[ct] = b[ct * 16 + colb];
    gam[ct]  = gamma[ct * 16 + colb];
    bet[ct]  = beta[ct * 16 + colb];
  }
#pragma unroll
  for (int r = 0; r < 4; ++r) {
    float vals[8];
    float S = 0.f, S2 = 0.f;
#pragma unroll
    for (int ct = 0; ct < 8; ++ct) {
      float v = acc[ct][r] + bias[ct];
      vals[ct] = v;
      S += v;
      S2 += v * v;
    }
#pragma unroll
    for (int off = 1; off < 16; off <<= 1) {   // reduce across the 16 lanes sharing this row
      S  += __shfl_xor(S, off);
      S2 += __shfl_xor(S2, off);
    }
    float mu  = S * (1.f / H);
    float var = S2 * (1.f / H) - mu * mu;
    float inv = rsqrtf(var + EPS);
    int grow = rowbase + kg * 4 + r;
    if (grow < N) {
#pragma unroll
      for (int ct = 0; ct < 8; ++ct)
        out[(size_t)grow * H + ct * 16 + colb] = (vals[ct] - mu) * inv * gam[ct] + bet[ct];
    }
  }
}

extern "C" void kernel_launch(void* const* d_in, const int* in_sizes, int n_in,
                              void* d_out, int out_size, void* d_ws, size_t ws_size,
                              hipStream_t stream) {
  const float* x         = (const float*)d_in[0];
  const float* edge_attr = (const float*)d_in[1];
  const int*   eidx      = (const int*)d_in[2];      // int32 (harness-converted)
  const float* W_node    = (const float*)d_in[3];
  const float* b_node    = (const float*)d_in[4];
  const float* W_edge    = (const float*)d_in[5];
  const float* b_edge    = (const float*)d_in[6];
  const float* W_conv    = (const float*)d_in[7];    // [3,128,128]
  const float* b_conv    = (const float*)d_in[8];    // [3,128]
  const float* W_head    = (const float*)d_in[9];
  const float* b_head    = (const float*)d_in[10];
  const float* gamma     = (const float*)d_in[11];
  const float* beta      = (const float*)d_in[12];
  float* out = (float*)d_out;

  // ---- workspace layout (R10 footprint, ~136.3 MB) ----
  size_t S = (size_t)N * H;                  // 12.8M elems
  __half* h_hi    = (__half*)d_ws;           // 25.6 MB
  __half* h_lo    = h_hi + S;                // 25.6 MB
  __half* skip_hi = h_lo + S;                // 25.6 MB
  uint4*  csr_a16 = (uint4*)(skip_hi + S);   // 51.2 MB (E x 32B)
  int*    csr_src = (int*)(csr_a16 + 2 * (size_t)E);  // 6.4 MB
  int*    deg     = csr_src + E;
  int*    excl    = deg + N;
  int*    rowptr  = excl + N;
  int*    cursor  = rowptr + N;
  int*    bsum    = cursor + N;
  int*    boff    = bsum + 512;
  __half* Wp_hi   = (__half*)(boff + 512);   // 4 mats x 16384 halfs = 128 KB
  __half* Wp_lo   = Wp_hi + 4 * 16384;       // 128 KB
  __half* sum_hi  = (__half*)out;            // d_out doubles as layer scratch (hi/lo halves)
  __half* sum_lo  = sum_hi + S;

  const int eb = (E + 255) / 256;            // 6250

  // ---- weight pack + CSR build (once) ----
  k_pack_w<<<256, 256, 0, stream>>>(W_conv, W_head, Wp_hi, Wp_lo);
  k_zero<<<NB, 256, 0, stream>>>(deg, N);
  k_hist<<<eb, 256, 0, stream>>>(eidx, deg);
  k_scan_block<<<NB, 256, 0, stream>>>(deg, excl, bsum);
  k_scan_top<<<1, 512, 0, stream>>>(bsum, boff);
  k_scan_add<<<NB, 256, 0, stream>>>(excl, boff, rowptr, cursor);
  k_scatter<<<eb, 256, 0, stream>>>(eidx, edge_attr, cursor, csr_src, csr_a16);

  // ---- network ----
  k_node_linear<<<N / 32, 256, 0, stream>>>(x, W_node, b_node, skip_hi);

  for (int l = 0; l < 3; ++l) {
    const __half* selfh = (l == 0) ? skip_hi : h_hi;
    const __half* selfl = (l == 0) ? nullptr : h_lo;
    const __half* nbr   = (l == 0) ? skip_hi : h_hi;
    k_gather<<<N / 4, 256, 0, stream>>>(rowptr, deg, csr_src, csr_a16,
                                        (const __half2*)nbr, W_edge, b_edge,
                                        (const __half2*)selfh, (const __half2*)selfl,
                                        (__half2*)sum_hi, (__half2*)sum_lo);
    k_update_mfma<<<NBM, 256, 0, stream>>>(
        sum_hi, sum_lo,
        (const uint4*)(Wp_hi + (size_t)l * 16384), (const uint4*)(Wp_lo + (size_t)l * 16384),
        b_conv + (size_t)l * H, h_hi, h_lo);
  }

  k_head_mfma<<<NBM, 256, 0, stream>>>(
      skip_hi, h_hi, h_lo,
      (const uint4*)(Wp_hi + 3 * (size_t)16384), (const uint4*)(Wp_lo + 3 * (size_t)16384),
      b_head, gamma, beta, out);
}

// Round 6
// 728.236 us; speedup vs baseline: 1.6283x; 1.0761x over previous
//
#include <hip/hip_runtime.h>
#include <hip/hip_fp16.h>

// GraphEncoder: node linear; 3x GINEConv(eps=0, nn=Linear+LeakyReLU); skip; head Linear+LayerNorm.
// R14: fuse update into gather (bit-identical relocation; the precision cliff forbids any
//      accumulation-order change). Block = 16 nodes, 4 waves x 4 nodes each with R13's exact
//      edge loop; fp32 acc -> same hi/lo split -> LDS tile; barrier; same MFMA chain (wave w
//      owns ct {2w,2w+1}; identical A rows + B frags + ks order => identical D). Kills the
//      sum hi/lo HBM round trip (102.4 MB/layer) + 3 launches. h ping-pong: A=ws pair,
//      B=d_out pair; skip->A->B->A; head reads skip+A, writes d_out(=dead B). No aliasing.
//      k_head_mfma stays R10-verbatim (LN reduce order = the cliff; do not touch).
// edge_index arrives as int32 (harness converts int64 inputs).
constexpr int N      = 100000;
constexpr int E      = 1600000;
constexpr int F_IN   = 64;
constexpr int F_EDGE = 16;
constexpr int H      = 128;
constexpr int NB     = (N + 255) / 256;     // 391 scan blocks
constexpr int NBM    = (N + 63) / 64;       // 1563 head blocks (64 rows each)
constexpr float NEG  = 0.01f;
constexpr float EPS  = 1e-5f;

typedef _Float16 hv2   __attribute__((ext_vector_type(2)));
typedef _Float16 f16x8 __attribute__((ext_vector_type(8)));
typedef float    f32x4 __attribute__((ext_vector_type(4)));

// ================= CSR build =================
__global__ __launch_bounds__(256) void k_zero(int* __restrict__ p, int n) {
  int i = blockIdx.x * 256 + threadIdx.x;
  if (i < n) p[i] = 0;
}

__global__ __launch_bounds__(256) void k_hist(const int* __restrict__ eidx, int* __restrict__ deg) {
  int i = blockIdx.x * 256 + threadIdx.x;
  if (i < E) atomicAdd(&deg[eidx[E + i]], 1);
}

__global__ __launch_bounds__(256) void k_scan_block(const int* __restrict__ deg,
    int* __restrict__ excl, int* __restrict__ bsum) {
  __shared__ int s[256];
  int t = threadIdx.x, i = blockIdx.x * 256 + t;
  int v = (i < N) ? deg[i] : 0;
  s[t] = v; __syncthreads();
#pragma unroll
  for (int off = 1; off < 256; off <<= 1) {
    int u = (t >= off) ? s[t - off] : 0;
    __syncthreads();
    s[t] += u;
    __syncthreads();
  }
  if (i < N) excl[i] = s[t] - v;
  if (t == 255) bsum[blockIdx.x] = s[255];
}

__global__ __launch_bounds__(512) void k_scan_top(const int* __restrict__ bsum, int* __restrict__ boff) {
  __shared__ int s[512];
  int t = threadIdx.x;
  int v = (t < NB) ? bsum[t] : 0;
  s[t] = v; __syncthreads();
#pragma unroll
  for (int off = 1; off < 512; off <<= 1) {
    int u = (t >= off) ? s[t - off] : 0;
    __syncthreads();
    s[t] += u;
    __syncthreads();
  }
  if (t < NB) boff[t] = s[t] - v;
}

__global__ __launch_bounds__(256) void k_scan_add(const int* __restrict__ excl,
    const int* __restrict__ boff, int* __restrict__ rowptr, int* __restrict__ cursor) {
  int i = blockIdx.x * 256 + threadIdx.x;
  if (i < N) {
    int r = excl[i] + boff[i >> 8];
    rowptr[i] = r;
    cursor[i] = r;
  }
}

// scatter: CSR-slot src index + edge_attr row converted to fp16 (2x uint4 = 32B/edge)
__global__ __launch_bounds__(256) void k_scatter(const int* __restrict__ eidx,
    const float* __restrict__ edge_attr, int* __restrict__ cursor,
    int* __restrict__ csr_src, uint4* __restrict__ csr_a16) {
  int i = blockIdx.x * 256 + threadIdx.x;
  if (i >= E) return;
  int d = eidx[E + i];
  int pos = atomicAdd(&cursor[d], 1);
  csr_src[pos] = eidx[i];
  const float4* ar = (const float4*)(edge_attr + (size_t)i * F_EDGE);
  float4 f0 = ar[0], f1 = ar[1], f2 = ar[2], f3 = ar[3];
  __half2 hh[8];
  hh[0] = __float22half2_rn(make_float2(f0.x, f0.y));
  hh[1] = __float22half2_rn(make_float2(f0.z, f0.w));
  hh[2] = __float22half2_rn(make_float2(f1.x, f1.y));
  hh[3] = __float22half2_rn(make_float2(f1.z, f1.w));
  hh[4] = __float22half2_rn(make_float2(f2.x, f2.y));
  hh[5] = __float22half2_rn(make_float2(f2.z, f2.w));
  hh[6] = __float22half2_rn(make_float2(f3.x, f3.y));
  hh[7] = __float22half2_rn(make_float2(f3.z, f3.w));
  const uint4* u = (const uint4*)hh;
  csr_a16[2 * (size_t)pos + 0] = u[0];
  csr_a16[2 * (size_t)pos + 1] = u[1];
}

// ================= weight pack -> MFMA B-frag fp16 hi/lo =================
// mats 0..2 (W_conv[l]): NEW layout, element = W[ks*32+(lane>>4)*8+e][(lane&15)*8 + ct].
// mat 3 (W_head): R10 layout, element = W[ks*32+(lane>>4)*8+e][ct*16 + (lane&15)]
//   (k_head_mfma is the R10 kernel verbatim -> LN order bit-identical to the passing run).
// half index = ((ks*8+ct)*64 + lane)*8 + e.
__global__ __launch_bounds__(256) void k_pack_w(
    const float* __restrict__ W_conv, const float* __restrict__ W_head,
    __half* __restrict__ Wp_hi, __half* __restrict__ Wp_lo) {
  int t = blockIdx.x * 256 + threadIdx.x;     // [0, 4*16384)
  int mat = t >> 14;
  int r = t & 16383;
  int e = r & 7, lane = (r >> 3) & 63, ct = (r >> 9) & 7, ks = (r >> 12) & 3;
  int k = ks * 32 + (lane >> 4) * 8 + e;
  int col = (mat < 3) ? ((lane & 15) * 8 + ct) : (ct * 16 + (lane & 15));
  const float* src = (mat < 3) ? (W_conv + (size_t)mat * H * H) : W_head;
  float v = src[k * H + col];
  __half hi = __float2half(v);
  __half lo = __float2half(v - __half2float(hi));
  Wp_hi[t] = hi;
  Wp_lo[t] = lo;
}

// ================= node linear (fp32, R10 lineage): skip = x @ W_node + b, fp16 hi out =================
__global__ __launch_bounds__(256) void k_node_linear(
    const float* __restrict__ x, const float* __restrict__ W,
    const float* __restrict__ b, __half* __restrict__ skip_hi) {
  __shared__ float xs[32][F_IN];             // 8 KB
  int i0 = blockIdx.x * 32;
  {
    const float4* s4 = (const float4*)(x + (size_t)i0 * F_IN);
    float4* t4 = (float4*)xs;
#pragma unroll
    for (int r = 0; r < 2; ++r) t4[threadIdx.x + 256 * r] = s4[threadIdx.x + 256 * r];
  }
  __syncthreads();
  int c0 = (threadIdx.x & 31) * 4;
  int n0 = (threadIdx.x >> 5) * 4;
  float4 bb = *(const float4*)(b + c0);
  float4 acc[4] = {bb, bb, bb, bb};
#pragma unroll 4
  for (int k = 0; k < F_IN; ++k) {
    float4 w4 = *(const float4*)(W + k * H + c0);   // coalesced; reused by 4 nodes
#pragma unroll
    for (int j = 0; j < 4; ++j) {
      float s = xs[n0 + j][k];                      // LDS broadcast
      acc[j].x = fmaf(s, w4.x, acc[j].x);
      acc[j].y = fmaf(s, w4.y, acc[j].y);
      acc[j].z = fmaf(s, w4.z, acc[j].z);
      acc[j].w = fmaf(s, w4.w, acc[j].w);
    }
  }
#pragma unroll
  for (int j = 0; j < 4; ++j) {
    size_t idx = (size_t)(i0 + n0 + j) * H + c0;
    __half2* ph = (__half2*)(skip_hi + idx);
    ph[0] = __float22half2_rn(make_float2(acc[j].x, acc[j].y));
    ph[1] = __float22half2_rn(make_float2(acc[j].z, acc[j].w));
  }
}

// ================= fused gather+update =================
// Phase 1 (per wave, 4 nodes sequentially, R13's exact edge loop): fp32 acc -> exact hi/lo
// split -> LDS tile [16 nodes][128ch] (half2, 8-half row pad for b128 alignment + bank spread).
// Phase 2: barrier; MFMA update h = leaky_relu(sum @ W + b); wave w computes ct {2w, 2w+1}.
// Bit-identical to R13's k_gather + k_update_mfma (same values, same per-element order).
__device__ __forceinline__ void dot16(uint4 A0, uint4 A1,
                                      const hv2* __restrict__ wA, const hv2* __restrict__ wB,
                                      float& tx, float& ty) {
  unsigned u[8] = {A0.x, A0.y, A0.z, A0.w, A1.x, A1.y, A1.z, A1.w};
#pragma unroll
  for (int j = 0; j < 8; ++j) {
    hv2 a = __builtin_bit_cast(hv2, u[j]);
    tx = __builtin_amdgcn_fdot2(a, wA[j], tx, false);
    ty = __builtin_amdgcn_fdot2(a, wB[j], ty, false);
  }
}

__global__ __launch_bounds__(256) void k_gather_update(
    const int* __restrict__ rowptr, const int* __restrict__ deg,
    const int* __restrict__ csr_src, const uint4* __restrict__ csr_a16,
    const __half2* __restrict__ nbr, const float* __restrict__ We,
    const float* __restrict__ be,
    const __half2* __restrict__ self_hi, const __half2* __restrict__ self_lo,
    const uint4* __restrict__ Wph, const uint4* __restrict__ Wpl,
    const float* __restrict__ b,
    __half* __restrict__ Ohi, __half* __restrict__ Olo) {
  __shared__ __half2 lds_hi[16][68];         // 68 half2/row = 272B stride (17x16B: aligned b128)
  __shared__ __half2 lds_lo[16][68];
  int lane = threadIdx.x & 63;
  int w = threadIdx.x >> 6;
  int c0 = 2 * lane;
  hv2 wA[8], wB[8];                          // We columns c0,c0+1 packed as k-pairs (lane-const)
#pragma unroll
  for (int j = 0; j < 8; ++j) {
    hv2 a, bq;
    a[0]  = (_Float16)We[(2 * j) * H + c0];
    a[1]  = (_Float16)We[(2 * j + 1) * H + c0];
    bq[0] = (_Float16)We[(2 * j) * H + c0 + 1];
    bq[1] = (_Float16)We[(2 * j + 1) * H + c0 + 1];
    wA[j] = a; wB[j] = bq;
  }
  float2 bias = ((const float2*)be)[lane];

  // ---- phase 1: gather 4 nodes (R13 edge loop, verbatim per node) ----
  for (int j4 = 0; j4 < 4; ++j4) {
    int node = blockIdx.x * 16 + w * 4 + j4;
    float2 acc;
    {
      float2 a = __half22float2(self_hi[(size_t)node * 64 + lane]);
      if (self_lo) {                         // wave-uniform scalar branch
        float2 l = __half22float2(self_lo[(size_t)node * 64 + lane]);
        a.x += l.x; a.y += l.y;
      }
      acc = a;
    }
    int p    = __builtin_amdgcn_readfirstlane(rowptr[node]);
    int dg   = __builtin_amdgcn_readfirstlane(deg[node]);
    int pend = p + dg;
    for (; p + 4 <= pend; p += 4) {
      int s0 = csr_src[p + 0];
      int s1 = csr_src[p + 1];
      int s2 = csr_src[p + 2];
      int s3 = csr_src[p + 3];
      __half2 g0 = nbr[(size_t)s0 * 64 + lane];   // 4 independent random 256B/wave gathers
      __half2 g1 = nbr[(size_t)s1 * 64 + lane];
      __half2 g2 = nbr[(size_t)s2 * 64 + lane];
      __half2 g3 = nbr[(size_t)s3 * 64 + lane];
      uint4 A0 = csr_a16[2 * (size_t)p + 0];      // wave-uniform sequential stream (scalar path)
      uint4 A1 = csr_a16[2 * (size_t)p + 1];
      uint4 B0 = csr_a16[2 * (size_t)p + 2];
      uint4 B1 = csr_a16[2 * (size_t)p + 3];
      uint4 C0 = csr_a16[2 * (size_t)p + 4];
      uint4 C1 = csr_a16[2 * (size_t)p + 5];
      uint4 D0 = csr_a16[2 * (size_t)p + 6];
      uint4 D1 = csr_a16[2 * (size_t)p + 7];
      float t0x = bias.x, t0y = bias.y;
      float t1x = bias.x, t1y = bias.y;
      float t2x = bias.x, t2y = bias.y;
      float t3x = bias.x, t3y = bias.y;
      dot16(A0, A1, wA, wB, t0x, t0y);
      dot16(B0, B1, wA, wB, t1x, t1y);
      dot16(C0, C1, wA, wB, t2x, t2y);
      dot16(D0, D1, wA, wB, t3x, t3y);
      float2 f0 = __half22float2(g0);
      float2 f1 = __half22float2(g1);
      float2 f2 = __half22float2(g2);
      float2 f3 = __half22float2(g3);
      acc.x += fmaxf(f0.x + t0x, 0.f) + fmaxf(f1.x + t1x, 0.f)
             + fmaxf(f2.x + t2x, 0.f) + fmaxf(f3.x + t3x, 0.f);
      acc.y += fmaxf(f0.y + t0y, 0.f) + fmaxf(f1.y + t1y, 0.f)
             + fmaxf(f2.y + t2y, 0.f) + fmaxf(f3.y + t3y, 0.f);
    }
    for (; p + 2 <= pend; p += 2) {
      int s0 = csr_src[p];
      int s1 = csr_src[p + 1];
      __half2 g0 = nbr[(size_t)s0 * 64 + lane];
      __half2 g1 = nbr[(size_t)s1 * 64 + lane];
      uint4 A0 = csr_a16[2 * (size_t)p + 0];
      uint4 A1 = csr_a16[2 * (size_t)p + 1];
      uint4 B0 = csr_a16[2 * (size_t)p + 2];
      uint4 B1 = csr_a16[2 * (size_t)p + 3];
      float t0x = bias.x, t0y = bias.y;
      float t1x = bias.x, t1y = bias.y;
      dot16(A0, A1, wA, wB, t0x, t0y);
      dot16(B0, B1, wA, wB, t1x, t1y);
      float2 gf0 = __half22float2(g0);
      float2 gf1 = __half22float2(g1);
      acc.x += fmaxf(gf0.x + t0x, 0.f) + fmaxf(gf1.x + t1x, 0.f);
      acc.y += fmaxf(gf0.y + t0y, 0.f) + fmaxf(gf1.y + t1y, 0.f);
    }
    for (; p < pend; ++p) {
      int s = csr_src[p];
      __half2 g = nbr[(size_t)s * 64 + lane];
      uint4 A0 = csr_a16[2 * (size_t)p + 0];
      uint4 A1 = csr_a16[2 * (size_t)p + 1];
      float tx = bias.x, ty = bias.y;
      dot16(A0, A1, wA, wB, tx, ty);
      float2 gf = __half22float2(g);
      acc.x += fmaxf(gf.x + tx, 0.f);
      acc.y += fmaxf(gf.y + ty, 0.f);
    }
    // exact hi/lo split (same arithmetic as R13's global write)
    __half2 hh = __float22half2_rn(acc);
    float2 rf = __half22float2(hh);
    __half2 hl = __float22half2_rn(make_float2(acc.x - rf.x, acc.y - rf.y));
    lds_hi[w * 4 + j4][lane] = hh;
    lds_lo[w * 4 + j4][lane] = hl;
  }
  __syncthreads();

  // ---- phase 2: MFMA update on the 16-row tile; wave w owns ct {2w, 2w+1} ----
  int r16 = lane & 15;
  int kg  = lane >> 4;
  f16x8 a_hi[4], a_lo[4];
  {
    const uint4* ph = (const uint4*)(&lds_hi[r16][0]);
    const uint4* pl = (const uint4*)(&lds_lo[r16][0]);
#pragma unroll
    for (int ks = 0; ks < 4; ++ks) {
      a_hi[ks] = __builtin_bit_cast(f16x8, ph[ks * 4 + kg]);
      a_lo[ks] = __builtin_bit_cast(f16x8, pl[ks * 4 + kg]);
    }
  }
  f32x4 acc2[2];
#pragma unroll
  for (int q = 0; q < 2; ++q) {
    acc2[q] = {0.f, 0.f, 0.f, 0.f};
    int ct = 2 * w + q;
#pragma unroll
    for (int ks = 0; ks < 4; ++ks) {
      f16x8 bh = __builtin_bit_cast(f16x8, Wph[(ks * 8 + ct) * 64 + lane]);
      f16x8 bl = __builtin_bit_cast(f16x8, Wpl[(ks * 8 + ct) * 64 + lane]);
      acc2[q] = __builtin_amdgcn_mfma_f32_16x16x32_f16(a_hi[ks], bh, acc2[q], 0, 0, 0);
      acc2[q] = __builtin_amdgcn_mfma_f32_16x16x32_f16(a_lo[ks], bh, acc2[q], 0, 0, 0);
      acc2[q] = __builtin_amdgcn_mfma_f32_16x16x32_f16(a_hi[ks], bl, acc2[q], 0, 0, 0);
    }
  }
  int colc = r16 * 8 + 2 * w;                // matrix cols colc, colc+1 (adjacent)
  float b0 = b[colc], b1 = b[colc + 1];
#pragma unroll
  for (int r = 0; r < 4; ++r) {
    int grow = blockIdx.x * 16 + kg * 4 + r;
    float y0 = acc2[0][r] + b0;
    float y1 = acc2[1][r] + b1;
    y0 = y0 >= 0.f ? y0 : NEG * y0;
    y1 = y1 >= 0.f ? y1 : NEG * y1;
    __half2 h2 = __float22half2_rn(make_float2(y0, y1));
    float2 rf = __half22float2(h2);
    __half2 l2 = __float22half2_rn(make_float2(y0 - rf.x, y1 - rf.y));
    *(__half2*)(Ohi + (size_t)grow * H + colc) = h2;
    *(__half2*)(Olo + (size_t)grow * H + colc) = l2;
  }
}

// ================= head (MFMA, R10 VERBATIM): t = skip + hfin; y = t @ W_head + b; LayerNorm ====
// R10 layout (col=ct*16+colb), R10 LN reduction order, R10 store pattern -> output bit-identical
// to the R10 passing run. Do NOT touch the LN arithmetic order (bf16-boundary cliff).
__global__ __launch_bounds__(256) void k_head_mfma(
    const __half* __restrict__ Shi, const __half* __restrict__ Hhi,
    const __half* __restrict__ Hlo,
    const uint4* __restrict__ Wph, const uint4* __restrict__ Wpl,
    const float* __restrict__ b, const float* __restrict__ gamma,
    const float* __restrict__ beta, float* __restrict__ out) {
  int lane = threadIdx.x & 63;
  int wv = threadIdx.x >> 6;
  int rowbase = blockIdx.x * 64 + wv * 16;
  int arow = rowbase + (lane & 15);
  if (arow >= N) arow = N - 1;
  int kg = lane >> 4;
  const uint4* ps = (const uint4*)(Shi + (size_t)arow * H);
  const uint4* ph = (const uint4*)(Hhi + (size_t)arow * H);
  const uint4* pl = (const uint4*)(Hlo + (size_t)arow * H);
  f16x8 a_hi[4], a_lo[4];
#pragma unroll
  for (int ks = 0; ks < 4; ++ks) {
    f16x8 s8 = __builtin_bit_cast(f16x8, ps[ks * 4 + kg]);
    f16x8 h8 = __builtin_bit_cast(f16x8, ph[ks * 4 + kg]);
    f16x8 l8 = __builtin_bit_cast(f16x8, pl[ks * 4 + kg]);
    f16x8 th, tl;
#pragma unroll
    for (int e = 0; e < 8; ++e) {
      float t = (float)s8[e] + (float)h8[e] + (float)l8[e];
      _Float16 hi = (_Float16)t;
      th[e] = hi;
      tl[e] = (_Float16)(t - (float)hi);
    }
    a_hi[ks] = th;
    a_lo[ks] = tl;
  }
  f32x4 acc[8];
#pragma unroll
  for (int ct = 0; ct < 8; ++ct) acc[ct] = {0.f, 0.f, 0.f, 0.f};
#pragma unroll
  for (int ct = 0; ct < 8; ++ct) {
#pragma unroll
    for (int ks = 0; ks < 4; ++ks) {
      f16x8 bh = __builtin_bit_cast(f16x8, Wph[(ks * 8 + ct) * 64 + lane]);
      f16x8 bl = __builtin_bit_cast(f16x8, Wpl[(ks * 8 + ct) * 64 + lane]);
      acc[ct] = __builtin_amdgcn_mfma_f32_16x16x32_f16(a_hi[ks], bh, acc[ct], 0, 0, 0);
      acc[ct] = __builtin_amdgcn_mfma_f32_16x16x32_f16(a_lo[ks], bh, acc[ct], 0, 0, 0);
      acc[ct] = __builtin_amdgcn_mfma_f32_16x16x32_f16(a_hi[ks], bl, acc[ct], 0, 0, 0);
    }
  }
  // LayerNorm epilogue: row r of this tile lives in acc[ct][r] across the 16 lanes of group kg.
  int colb = lane & 15;
  float bias[8], gam[8], bet[8];
#pragma unroll
  for (int ct = 0; ct < 8; ++ct) {
    bias[ct] = b[ct * 16 + colb];
    gam[ct]  = gamma[ct * 16 + colb];
    bet[ct]  = beta[ct * 16 + colb];
  }
#pragma unroll
  for (int r = 0; r < 4; ++r) {
    float vals[8];
    float S = 0.f, S2 = 0.f;
#pragma unroll
    for (int ct = 0; ct < 8; ++ct) {
      float v = acc[ct][r] + bias[ct];
      vals[ct] = v;
      S += v;
      S2 += v * v;
    }
#pragma unroll
    for (int off = 1; off < 16; off <<= 1) {   // reduce across the 16 lanes sharing this row
      S  += __shfl_xor(S, off);
      S2 += __shfl_xor(S2, off);
    }
    float mu  = S * (1.f / H);
    float var = S2 * (1.f / H) - mu * mu;
    float inv = rsqrtf(var + EPS);
    int grow = rowbase + kg * 4 + r;
    if (grow < N) {
#pragma unroll
      for (int ct = 0; ct < 8; ++ct)
        out[(size_t)grow * H + ct * 16 + colb] = (vals[ct] - mu) * inv * gam[ct] + bet[ct];
    }
  }
}

extern "C" void kernel_launch(void* const* d_in, const int* in_sizes, int n_in,
                              void* d_out, int out_size, void* d_ws, size_t ws_size,
                              hipStream_t stream) {
  const float* x         = (const float*)d_in[0];
  const float* edge_attr = (const float*)d_in[1];
  const int*   eidx      = (const int*)d_in[2];      // int32 (harness-converted)
  const float* W_node    = (const float*)d_in[3];
  const float* b_node    = (const float*)d_in[4];
  const float* W_edge    = (const float*)d_in[5];
  const float* b_edge    = (const float*)d_in[6];
  const float* W_conv    = (const float*)d_in[7];    // [3,128,128]
  const float* b_conv    = (const float*)d_in[8];    // [3,128]
  const float* W_head    = (const float*)d_in[9];
  const float* b_head    = (const float*)d_in[10];
  const float* gamma     = (const float*)d_in[11];
  const float* beta      = (const float*)d_in[12];
  float* out = (float*)d_out;

  // ---- workspace layout (R13 footprint minus sum scratch) ----
  size_t S = (size_t)N * H;                  // 12.8M elems
  __half* hA_hi   = (__half*)d_ws;           // 25.6 MB (ping pair A)
  __half* hA_lo   = hA_hi + S;               // 25.6 MB
  __half* skip_hi = hA_lo + S;               // 25.6 MB
  uint4*  csr_a16 = (uint4*)(skip_hi + S);   // 51.2 MB (E x 32B)
  int*    csr_src = (int*)(csr_a16 + 2 * (size_t)E);  // 6.4 MB
  int*    deg     = csr_src + E;
  int*    excl    = deg + N;
  int*    rowptr  = excl + N;
  int*    cursor  = rowptr + N;
  int*    bsum    = cursor + N;
  int*    boff    = bsum + 512;
  __half* Wp_hi   = (__half*)(boff + 512);   // 4 mats x 16384 halfs = 128 KB
  __half* Wp_lo   = Wp_hi + 4 * 16384;       // 128 KB
  __half* hB_hi   = (__half*)out;            // pong pair B in d_out (dead at head-write time)
  __half* hB_lo   = hB_hi + S;

  const int eb = (E + 255) / 256;            // 6250

  // ---- weight pack + CSR build (once) ----
  k_pack_w<<<256, 256, 0, stream>>>(W_conv, W_head, Wp_hi, Wp_lo);
  k_zero<<<NB, 256, 0, stream>>>(deg, N);
  k_hist<<<eb, 256, 0, stream>>>(eidx, deg);
  k_scan_block<<<NB, 256, 0, stream>>>(deg, excl, bsum);
  k_scan_top<<<1, 512, 0, stream>>>(bsum, boff);
  k_scan_add<<<NB, 256, 0, stream>>>(excl, boff, rowptr, cursor);
  k_scatter<<<eb, 256, 0, stream>>>(eidx, edge_attr, cursor, csr_src, csr_a16);

  // ---- network ----
  k_node_linear<<<N / 32, 256, 0, stream>>>(x, W_node, b_node, skip_hi);

  // layer 0: skip -> A
  k_gather_update<<<N / 16, 256, 0, stream>>>(rowptr, deg, csr_src, csr_a16,
      (const __half2*)skip_hi, W_edge, b_edge,
      (const __half2*)skip_hi, (const __half2*)nullptr,
      (const uint4*)(Wp_hi + 0 * (size_t)16384), (const uint4*)(Wp_lo + 0 * (size_t)16384),
      b_conv + 0 * H, hA_hi, hA_lo);
  // layer 1: A -> B
  k_gather_update<<<N / 16, 256, 0, stream>>>(rowptr, deg, csr_src, csr_a16,
      (const __half2*)hA_hi, W_edge, b_edge,
      (const __half2*)hA_hi, (const __half2*)hA_lo,
      (const uint4*)(Wp_hi + 1 * (size_t)16384), (const uint4*)(Wp_lo + 1 * (size_t)16384),
      b_conv + 1 * H, hB_hi, hB_lo);
  // layer 2: B -> A
  k_gather_update<<<N / 16, 256, 0, stream>>>(rowptr, deg, csr_src, csr_a16,
      (const __half2*)hB_hi, W_edge, b_edge,
      (const __half2*)hB_hi, (const __half2*)hB_lo,
      (const uint4*)(Wp_hi + 2 * (size_t)16384), (const uint4*)(Wp_lo + 2 * (size_t)16384),
      b_conv + 2 * H, hA_hi, hA_lo);

  k_head_mfma<<<NBM, 256, 0, stream>>>(
      skip_hi, hA_hi, hA_lo,
      (const uint4*)(Wp_hi + 3 * (size_t)16384), (const uint4*)(Wp_lo + 3 * (size_t)16384),
      b_head, gamma, beta, out);
}